// Round 1
// baseline (1802.007 us; speedup 1.0000x reference)
//
#include <hip/hip_runtime.h>

// ---------------------------------------------------------------------------
// HeteroGNN (GAT x3 + transform x2) on MI355X — Round 1 baseline (all fp32).
//
// Decomposition:
//   1. Vd precompute:      Vd[k,h] = sum_c W[k, h*32+c] * a_dst[h,c]   (dst logits
//      collapse to x @ Vd — avoids materializing hd for cio/ioc relations)
//   2. gemm_h:  H = x @ W  [M,128], fused epilogue computes per-head logits
//      als/ald = (H_row,head . a_vec) via 4-lane shuffle reduction
//   3. gemv4:   ald = x @ Vd  (memory-bound pass over x)
//   4. edge_max: segment max via atomicMax on order-preserving uint encoding
//   5. edge_agg: ex = exp(e - m[d]); atomicAdd den[d,h]; atomicAdd
//      Num[d,:] += ex * Hs[s,:]   (numerator unnormalized — normalize later)
//   6. combine:  Y = Num1/den1 + Num2/den2 + b1 + b2   (in-place over Num1)
//   7. transform: out = Y + relu(LN(Y@Wt + bt)*g + be)  fused GEMM+LN+residual
// ---------------------------------------------------------------------------

#define NC   100000
#define NIO  2000
#define DD   128
#define ECC  600000
#define ECIO 50000
#define EIOC 50000

// ----- order-preserving float<->uint encoding for atomicMax ------------------
static __device__ __forceinline__ unsigned enc_f(float f) {
  unsigned u = __float_as_uint(f);
  return (u & 0x80000000u) ? ~u : (u | 0x80000000u);
}
static __device__ __forceinline__ float dec_f(unsigned u) {
  return (u & 0x80000000u) ? __uint_as_float(u & 0x7fffffffu)
                           : __uint_as_float(~u);
}
#define ENC_NEG_INF 0x007FFFFFu  // enc_f(-inf)

// ----- tiny fills ------------------------------------------------------------
__global__ void fill_u32(unsigned* __restrict__ p, unsigned v, int n) {
  int i = blockIdx.x * blockDim.x + threadIdx.x;
  int stride = gridDim.x * blockDim.x;
  for (; i < n; i += stride) p[i] = v;
}

// ----- Vd[k,h] = sum_c W[k, h*32+c]*ad[h*32+c]  (two matrices in one launch) -
__global__ void vd_compute(const float* __restrict__ W1, const float* __restrict__ ad1,
                           const float* __restrict__ W2, const float* __restrict__ ad2,
                           float* __restrict__ V1, float* __restrict__ V2) {
  int t = blockIdx.x * blockDim.x + threadIdx.x;  // 1024 threads total
  if (t >= 1024) return;
  const float* W  = (t < 512) ? W1 : W2;
  const float* ad = (t < 512) ? ad1 : ad2;
  float*       V  = (t < 512) ? V1 : V2;
  int i = t & 511;
  int k = i >> 2, h = i & 3;
  float s = 0.f;
#pragma unroll
  for (int c = 0; c < 32; ++c) s += W[k * 128 + h * 32 + c] * ad[h * 32 + c];
  V[k * 4 + h] = s;
}

// ----- register-blocked fp32 GEMM: H[M,128] = A[M,128] @ W[128,128] ----------
// block 256 thr, tile 128x128, micro 8x8, BK=8. Optional logit epilogue.
__global__ __launch_bounds__(256) void gemm_h(
    const float* __restrict__ A, int M, const float* __restrict__ W,
    float* __restrict__ Hout,
    const float* __restrict__ as_vec, float* __restrict__ als,
    const float* __restrict__ ad_vec, float* __restrict__ ald) {
  __shared__ float As[8][128];  // As[k][m]
  __shared__ float Bs[8][128];  // Bs[k][n]
  const int bm  = blockIdx.x * 128;
  const int tid = threadIdx.x;
  const int tr = tid >> 4, tc = tid & 15;
  float acc[8][8];
#pragma unroll
  for (int i = 0; i < 8; ++i)
#pragma unroll
    for (int j = 0; j < 8; ++j) acc[i][j] = 0.f;

  const int lrow = tid >> 1, lk4 = (tid & 1) * 4;
  const int arow = bm + lrow;
  const bool arow_ok = (arow < M);
  const int wk = tid >> 5, wn = (tid & 31) * 4;

  for (int k0 = 0; k0 < 128; k0 += 8) {
    float4 av = arow_ok ? *(const float4*)(A + (size_t)arow * 128 + k0 + lk4)
                        : make_float4(0.f, 0.f, 0.f, 0.f);
    As[lk4 + 0][lrow] = av.x;
    As[lk4 + 1][lrow] = av.y;
    As[lk4 + 2][lrow] = av.z;
    As[lk4 + 3][lrow] = av.w;
    *(float4*)(&Bs[wk][wn]) = *(const float4*)(W + (size_t)(k0 + wk) * 128 + wn);
    __syncthreads();
#pragma unroll
    for (int k = 0; k < 8; ++k) {
      float a[8], b[8];
      *(float4*)(a)     = *(const float4*)(&As[k][tr * 8]);
      *(float4*)(a + 4) = *(const float4*)(&As[k][tr * 8 + 4]);
      *(float4*)(b)     = *(const float4*)(&Bs[k][tc * 8]);
      *(float4*)(b + 4) = *(const float4*)(&Bs[k][tc * 8 + 4]);
#pragma unroll
      for (int i = 0; i < 8; ++i)
#pragma unroll
        for (int j = 0; j < 8; ++j) acc[i][j] += a[i] * b[j];
    }
    __syncthreads();
  }

  // store H
#pragma unroll
  for (int i = 0; i < 8; ++i) {
    int row = bm + tr * 8 + i;
    if (row < M) {
      float4 v0 = make_float4(acc[i][0], acc[i][1], acc[i][2], acc[i][3]);
      float4 v1 = make_float4(acc[i][4], acc[i][5], acc[i][6], acc[i][7]);
      *(float4*)(Hout + (size_t)row * 128 + tc * 8)     = v0;
      *(float4*)(Hout + (size_t)row * 128 + tc * 8 + 4) = v1;
    }
  }

  // fused per-head logits: all 8 of this thread's cols lie in head h = tc>>2
  if (als != nullptr) {
    int h = tc >> 2;
    float asv[8], adv[8];
#pragma unroll
    for (int j = 0; j < 8; ++j) asv[j] = as_vec[tc * 8 + j];
    if (ald != nullptr)
#pragma unroll
      for (int j = 0; j < 8; ++j) adv[j] = ad_vec[tc * 8 + j];
#pragma unroll
    for (int i = 0; i < 8; ++i) {
      int row = bm + tr * 8 + i;
      float s1 = 0.f, s2 = 0.f;
#pragma unroll
      for (int j = 0; j < 8; ++j) {
        s1 += acc[i][j] * asv[j];
        if (ald != nullptr) s2 += acc[i][j] * adv[j];
      }
      s1 += __shfl_xor(s1, 1); s1 += __shfl_xor(s1, 2);
      if (ald != nullptr) { s2 += __shfl_xor(s2, 1); s2 += __shfl_xor(s2, 2); }
      if ((tc & 3) == 0 && row < M) {
        als[row * 4 + h] = s1;
        if (ald != nullptr) ald[row * 4 + h] = s2;
      }
    }
  }
}

// ----- ald[n,h] = sum_k x[n,k] * Vd[k,h]  (one wave per row) -----------------
__global__ __launch_bounds__(256) void gemv4(const float* __restrict__ x, int M,
                                             const float* __restrict__ Vd,
                                             float* __restrict__ out) {
  int lane = threadIdx.x & 63;
  int wid  = (blockIdx.x * blockDim.x + threadIdx.x) >> 6;
  int nw   = (gridDim.x * blockDim.x) >> 6;
  float4 v0 = *(const float4*)(Vd + 8 * lane);      // Vd[2*lane][:]
  float4 v1 = *(const float4*)(Vd + 8 * lane + 4);  // Vd[2*lane+1][:]
  for (int row = wid; row < M; row += nw) {
    float2 xv = *(const float2*)(x + (size_t)row * 128 + 2 * lane);
    float p0 = xv.x * v0.x + xv.y * v1.x;
    float p1 = xv.x * v0.y + xv.y * v1.y;
    float p2 = xv.x * v0.z + xv.y * v1.z;
    float p3 = xv.x * v0.w + xv.y * v1.w;
#pragma unroll
    for (int off = 32; off >= 1; off >>= 1) {
      p0 += __shfl_xor(p0, off);
      p1 += __shfl_xor(p1, off);
      p2 += __shfl_xor(p2, off);
      p3 += __shfl_xor(p3, off);
    }
    if (lane == 0) *(float4*)(out + 4 * (size_t)row) = make_float4(p0, p1, p2, p3);
  }
}

// ----- per-edge segment max (order-preserving uint atomicMax) ----------------
__global__ void edge_max(const int* __restrict__ ei, int E,
                         const float* __restrict__ als, const float* __restrict__ ald,
                         unsigned* __restrict__ m) {
  int i = blockIdx.x * blockDim.x + threadIdx.x;
  int stride = gridDim.x * blockDim.x;
  for (; i < E; i += stride) {
    int s = ei[i], d = ei[E + i];
    float4 a = *(const float4*)(als + 4 * (size_t)s);
    float4 b = *(const float4*)(ald + 4 * (size_t)d);
    float e0 = a.x + b.x, e1 = a.y + b.y, e2 = a.z + b.z, e3 = a.w + b.w;
    e0 = e0 > 0.f ? e0 : 0.2f * e0;
    e1 = e1 > 0.f ? e1 : 0.2f * e1;
    e2 = e2 > 0.f ? e2 : 0.2f * e2;
    e3 = e3 > 0.f ? e3 : 0.2f * e3;
    atomicMax(m + 4 * (size_t)d + 0, enc_f(e0));
    atomicMax(m + 4 * (size_t)d + 1, enc_f(e1));
    atomicMax(m + 4 * (size_t)d + 2, enc_f(e2));
    atomicMax(m + 4 * (size_t)d + 3, enc_f(e3));
  }
}

// ----- fused exp + denominator + numerator accumulation ----------------------
// half-wave (32 lanes) per edge: lane c handles cols 4c..4c+3 (head c>>3)
__global__ void edge_agg(const int* __restrict__ ei, int E,
                         const float* __restrict__ als, const float* __restrict__ ald,
                         const unsigned* __restrict__ m, const float* __restrict__ Hs,
                         float* __restrict__ Num, float* __restrict__ den) {
  int tid = blockIdx.x * blockDim.x + threadIdx.x;
  int hw  = tid >> 5;
  int c   = tid & 31;
  int nhw = (gridDim.x * blockDim.x) >> 5;
  for (int e = hw; e < E; e += nhw) {
    int s = ei[e], d = ei[E + e];
    float4 a = *(const float4*)(als + 4 * (size_t)s);
    float4 b = *(const float4*)(ald + 4 * (size_t)d);
    float ex[4];
    {
      float ev[4] = {a.x + b.x, a.y + b.y, a.z + b.z, a.w + b.w};
#pragma unroll
      for (int h = 0; h < 4; ++h) {
        float v = ev[h] > 0.f ? ev[h] : 0.2f * ev[h];
        float mm = dec_f(m[4 * (size_t)d + h]);
        ex[h] = __expf(v - mm);
      }
    }
    if (c < 4) atomicAdd(den + 4 * (size_t)d + c, ex[c]);
    float4 v = *(const float4*)(Hs + (size_t)s * 128 + 4 * c);
    float sc = ex[c >> 3];
    float* np = Num + (size_t)d * 128 + 4 * c;
    atomicAdd(np + 0, sc * v.x);
    atomicAdd(np + 1, sc * v.y);
    atomicAdd(np + 2, sc * v.z);
    atomicAdd(np + 3, sc * v.w);
  }
}

// ----- Y = Num1/den1 [+ Num2/den2] + b1 [+ b2]   (in-place over Num1) --------
__global__ void combine(float* __restrict__ Y, const float* __restrict__ Num2,
                        const float* __restrict__ den1, const float* __restrict__ den2,
                        const float* __restrict__ b1, const float* __restrict__ b2,
                        int M) {
  int i = blockIdx.x * blockDim.x + threadIdx.x;
  int stride = gridDim.x * blockDim.x;
  int n4 = M * 32;
  for (; i < n4; i += stride) {
    int n = i >> 5, c4 = i & 31, h = c4 >> 3;
    float4 a = ((const float4*)Y)[i];
    float d1 = den1[n * 4 + h] + 1e-16f;
    float inv1 = 1.f / d1;
    float4 r;
    r.x = a.x * inv1; r.y = a.y * inv1; r.z = a.z * inv1; r.w = a.w * inv1;
    float4 bb = ((const float4*)b1)[c4];
    r.x += bb.x; r.y += bb.y; r.z += bb.z; r.w += bb.w;
    if (Num2 != nullptr) {
      float4 a2 = ((const float4*)Num2)[i];
      float inv2 = 1.f / (den2[n * 4 + h] + 1e-16f);
      float4 b2v = ((const float4*)b2)[c4];
      r.x += a2.x * inv2 + b2v.x;
      r.y += a2.y * inv2 + b2v.y;
      r.z += a2.z * inv2 + b2v.z;
      r.w += a2.w * inv2 + b2v.w;
    }
    ((float4*)Y)[i] = r;
  }
}

// ----- fused transform: out = Y + relu(LN(Y@Wt + bt)*g + be) -----------------
__global__ __launch_bounds__(256) void transform_k(
    const float* __restrict__ Y, int M, const float* __restrict__ Wt,
    const float* __restrict__ bt, const float* __restrict__ g,
    const float* __restrict__ be, float* __restrict__ out) {
  __shared__ float As[8][128];
  __shared__ float Bs[8][128];
  const int bm  = blockIdx.x * 128;
  const int tid = threadIdx.x;
  const int tr = tid >> 4, tc = tid & 15;
  float acc[8][8];
#pragma unroll
  for (int i = 0; i < 8; ++i)
#pragma unroll
    for (int j = 0; j < 8; ++j) acc[i][j] = 0.f;

  const int lrow = tid >> 1, lk4 = (tid & 1) * 4;
  const int arow = bm + lrow;
  const bool arow_ok = (arow < M);
  const int wk = tid >> 5, wn = (tid & 31) * 4;

  for (int k0 = 0; k0 < 128; k0 += 8) {
    float4 av = arow_ok ? *(const float4*)(Y + (size_t)arow * 128 + k0 + lk4)
                        : make_float4(0.f, 0.f, 0.f, 0.f);
    As[lk4 + 0][lrow] = av.x;
    As[lk4 + 1][lrow] = av.y;
    As[lk4 + 2][lrow] = av.z;
    As[lk4 + 3][lrow] = av.w;
    *(float4*)(&Bs[wk][wn]) = *(const float4*)(Wt + (size_t)(k0 + wk) * 128 + wn);
    __syncthreads();
#pragma unroll
    for (int k = 0; k < 8; ++k) {
      float a[8], b[8];
      *(float4*)(a)     = *(const float4*)(&As[k][tr * 8]);
      *(float4*)(a + 4) = *(const float4*)(&As[k][tr * 8 + 4]);
      *(float4*)(b)     = *(const float4*)(&Bs[k][tc * 8]);
      *(float4*)(b + 4) = *(const float4*)(&Bs[k][tc * 8 + 4]);
#pragma unroll
      for (int i = 0; i < 8; ++i)
#pragma unroll
        for (int j = 0; j < 8; ++j) acc[i][j] += a[i] * b[j];
    }
    __syncthreads();
  }

  // epilogue: + bt, LayerNorm over the 128-wide row (16 lanes), relu, residual
  float btv[8], gv[8], bev[8];
#pragma unroll
  for (int j = 0; j < 8; ++j) {
    btv[j] = bt[tc * 8 + j];
    gv[j]  = g[tc * 8 + j];
    bev[j] = be[tc * 8 + j];
  }
#pragma unroll
  for (int i = 0; i < 8; ++i) {
    int row = bm + tr * 8 + i;
    float hv[8];
    float s = 0.f, ss = 0.f;
#pragma unroll
    for (int j = 0; j < 8; ++j) {
      hv[j] = acc[i][j] + btv[j];
      s += hv[j];
      ss += hv[j] * hv[j];
    }
#pragma unroll
    for (int off = 1; off <= 8; off <<= 1) {
      s  += __shfl_xor(s, off);
      ss += __shfl_xor(ss, off);
    }
    float mu  = s * (1.f / 128.f);
    float var = ss * (1.f / 128.f) - mu * mu;
    float rs  = rsqrtf(var + 1e-5f);
    if (row < M) {
      float4 y0 = *(const float4*)(Y + (size_t)row * 128 + tc * 8);
      float4 y1 = *(const float4*)(Y + (size_t)row * 128 + tc * 8 + 4);
      float yv[8] = {y0.x, y0.y, y0.z, y0.w, y1.x, y1.y, y1.z, y1.w};
      float ov[8];
#pragma unroll
      for (int j = 0; j < 8; ++j) {
        float hn = (hv[j] - mu) * rs * gv[j] + bev[j];
        ov[j] = yv[j] + (hn > 0.f ? hn : 0.f);
      }
      *(float4*)(out + (size_t)row * 128 + tc * 8) =
          make_float4(ov[0], ov[1], ov[2], ov[3]);
      *(float4*)(out + (size_t)row * 128 + tc * 8 + 4) =
          make_float4(ov[4], ov[5], ov[6], ov[7]);
    }
  }
}

// ---------------------------------------------------------------------------
extern "C" void kernel_launch(void* const* d_in, const int* in_sizes, int n_in,
                              void* d_out, int out_size, void* d_ws, size_t ws_size,
                              hipStream_t stream) {
  const float* x_cell = (const float*)d_in[0];
  const float* x_io   = (const float*)d_in[1];
  const int*   ei_cc  = (const int*)d_in[2];
  const int*   ei_cio = (const int*)d_in[3];
  const int*   ei_ioc = (const int*)d_in[4];
  const float* W_cc   = (const float*)d_in[5];
  const float* as_cc  = (const float*)d_in[6];
  const float* ad_cc  = (const float*)d_in[7];
  const float* b_cc   = (const float*)d_in[8];
  const float* W_cio  = (const float*)d_in[9];
  const float* as_cio = (const float*)d_in[10];
  const float* ad_cio = (const float*)d_in[11];
  const float* b_cio  = (const float*)d_in[12];
  const float* W_ioc  = (const float*)d_in[13];
  const float* as_ioc = (const float*)d_in[14];
  const float* ad_ioc = (const float*)d_in[15];
  const float* b_ioc  = (const float*)d_in[16];
  const float* Wt_cell = (const float*)d_in[17];
  const float* bt_cell = (const float*)d_in[18];
  const float* g_cell  = (const float*)d_in[19];
  const float* be_cell = (const float*)d_in[20];
  const float* Wt_io   = (const float*)d_in[21];
  const float* bt_io   = (const float*)d_in[22];
  const float* g_io    = (const float*)d_in[23];
  const float* be_io   = (const float*)d_in[24];

  float* out_cell = (float*)d_out;               // [NC,128]
  float* out_io   = (float*)d_out + (size_t)NC * 128;  // [NIO,128]

  // ----- workspace layout (floats) -----  total ≈ 220 MB
  float* w = (float*)d_ws;
  size_t o = 0;
  float* Hcc     = w + o; o += (size_t)NC * 128;
  float* Hcio    = w + o; o += (size_t)NC * 128;
  float* Hioc    = w + o; o += (size_t)NIO * 128;
  float* als_cc  = w + o; o += (size_t)NC * 4;
  float* ald_cc  = w + o; o += (size_t)NC * 4;
  float* als_cio = w + o; o += (size_t)NC * 4;
  float* ald_ioc = w + o; o += (size_t)NC * 4;
  float* als_ioc = w + o; o += (size_t)NIO * 4;
  float* ald_cio = w + o; o += (size_t)NIO * 4;
  float* Vd_ioc  = w + o; o += 512;
  float* Vd_cio  = w + o; o += 512;
  size_t zstart = o;                      // ---- zero-init region ----
  float* Num_cc  = w + o; o += (size_t)NC * 128;
  float* Num_ioc = w + o; o += (size_t)NC * 128;
  float* Num_cio = w + o; o += (size_t)NIO * 128;
  float* den_cc  = w + o; o += (size_t)NC * 4;
  float* den_ioc = w + o; o += (size_t)NC * 4;
  float* den_cio = w + o; o += (size_t)NIO * 4;
  size_t zend = o;                        // ---- -inf-init region ----
  unsigned* m_cc  = (unsigned*)(w + o); o += (size_t)NC * 4;
  unsigned* m_ioc = (unsigned*)(w + o); o += (size_t)NC * 4;
  unsigned* m_cio = (unsigned*)(w + o); o += (size_t)NIO * 4;
  // (assumes ws_size >= o*4 ≈ 220 MB)

  // 1. init
  hipMemsetAsync(w + zstart, 0, (zend - zstart) * sizeof(float), stream);
  {
    int n = NC * 4 + NC * 4 + NIO * 4;
    fill_u32<<<1024, 256, 0, stream>>>(m_cc, ENC_NEG_INF, n);
  }
  vd_compute<<<4, 256, 0, stream>>>(W_ioc, ad_ioc, W_cio, ad_cio, Vd_ioc, Vd_cio);

  // 2. projections + fused logits
  gemm_h<<<(NC + 127) / 128, 256, 0, stream>>>(x_cell, NC, W_cc, Hcc,
                                               as_cc, als_cc, ad_cc, ald_cc);
  gemm_h<<<(NC + 127) / 128, 256, 0, stream>>>(x_cell, NC, W_cio, Hcio,
                                               as_cio, als_cio, nullptr, nullptr);
  gemm_h<<<(NIO + 127) / 128, 256, 0, stream>>>(x_io, NIO, W_ioc, Hioc,
                                                as_ioc, als_ioc, nullptr, nullptr);
  gemv4<<<2048, 256, 0, stream>>>(x_cell, NC, Vd_ioc, ald_ioc);
  gemv4<<<128, 256, 0, stream>>>(x_io, NIO, Vd_cio, ald_cio);

  // 3. segment max per relation
  edge_max<<<2344, 256, 0, stream>>>(ei_cc, ECC, als_cc, ald_cc, m_cc);
  edge_max<<<196, 256, 0, stream>>>(ei_ioc, EIOC, als_ioc, ald_ioc, m_ioc);
  edge_max<<<196, 256, 0, stream>>>(ei_cio, ECIO, als_cio, ald_cio, m_cio);

  // 4. fused exp + den + numerator accumulation
  edge_agg<<<4096, 256, 0, stream>>>(ei_cc, ECC, als_cc, ald_cc, m_cc, Hcc,
                                     Num_cc, den_cc);
  edge_agg<<<2048, 256, 0, stream>>>(ei_ioc, EIOC, als_ioc, ald_ioc, m_ioc, Hioc,
                                     Num_ioc, den_ioc);
  edge_agg<<<2048, 256, 0, stream>>>(ei_cio, ECIO, als_cio, ald_cio, m_cio, Hcio,
                                     Num_cio, den_cio);

  // 5. combine (normalize + biases); Y written in place over Num buffers
  combine<<<2048, 256, 0, stream>>>(Num_cc, Num_ioc, den_cc, den_ioc,
                                    b_cc, b_ioc, NC);
  combine<<<512, 256, 0, stream>>>(Num_cio, nullptr, den_cio, nullptr,
                                   b_cio, nullptr, NIO);

  // 6. transform (GEMM + LN + relu + residual) straight into d_out
  transform_k<<<(NC + 127) / 128, 256, 0, stream>>>(Num_cc, NC, Wt_cell,
                                                    bt_cell, g_cell, be_cell,
                                                    out_cell);
  transform_k<<<(NIO + 127) / 128, 256, 0, stream>>>(Num_cio, NIO, Wt_io,
                                                     bt_io, g_io, be_io,
                                                     out_io);
}

// Round 2
// 1047.509 us; speedup vs baseline: 1.7203x; 1.7203x over previous
//
#include <hip/hip_runtime.h>

// ---------------------------------------------------------------------------
// HeteroGNN (GAT x3 + transform x2) on MI355X — Round 2.
// R1 post-mortem: edge_agg scatter-atomics = 1046us (58%), WRITE_SIZE 1.22GB
// (24x ideal) -> atomic/RMW-bound. Fix: CSR-by-dest + wave-per-dest gather.
//
//   1. vd_compute: Vd[k,h] = sum_c W[k,h*32+c]*ad[h,c]  (dst logits = x @ Vd)
//   2. gemm_h: H = x@W with fused per-head logit epilogue (als/ald)
//   3. gemv4:  ald = x @ Vd for relations where hd is never materialized
//   4. CSR build per relation: hist -> single-WG exclusive scan -> scatter
//   5. dest_agg_cell / dest_agg_io: one wave per dest; register max/exp/den;
//      coalesced row gathers of Hs; ONE 512B write per dest (no float atomics)
//   6. transform: out = Y + relu(LN(Y@Wt + bt)*g + be)  fused GEMM+LN+residual
// ---------------------------------------------------------------------------

#define NC   100000
#define NIO  2000
#define ECC  600000
#define ECIO 50000
#define EIOC 50000

// ----- Vd[k,h] = sum_c W[k, h*32+c]*ad[h*32+c]  (two matrices in one launch) -
__global__ void vd_compute(const float* __restrict__ W1, const float* __restrict__ ad1,
                           const float* __restrict__ W2, const float* __restrict__ ad2,
                           float* __restrict__ V1, float* __restrict__ V2) {
  int t = blockIdx.x * blockDim.x + threadIdx.x;
  if (t >= 1024) return;
  const float* W  = (t < 512) ? W1 : W2;
  const float* ad = (t < 512) ? ad1 : ad2;
  float*       V  = (t < 512) ? V1 : V2;
  int i = t & 511;
  int k = i >> 2, h = i & 3;
  float s = 0.f;
#pragma unroll
  for (int c = 0; c < 32; ++c) s += W[k * 128 + h * 32 + c] * ad[h * 32 + c];
  V[k * 4 + h] = s;
}

// ----- register-blocked fp32 GEMM: H[M,128] = A[M,128] @ W[128,128] ----------
__global__ __launch_bounds__(256) void gemm_h(
    const float* __restrict__ A, int M, const float* __restrict__ W,
    float* __restrict__ Hout,
    const float* __restrict__ as_vec, float* __restrict__ als,
    const float* __restrict__ ad_vec, float* __restrict__ ald) {
  __shared__ float As[8][128];
  __shared__ float Bs[8][128];
  const int bm  = blockIdx.x * 128;
  const int tid = threadIdx.x;
  const int tr = tid >> 4, tc = tid & 15;
  float acc[8][8];
#pragma unroll
  for (int i = 0; i < 8; ++i)
#pragma unroll
    for (int j = 0; j < 8; ++j) acc[i][j] = 0.f;

  const int lrow = tid >> 1, lk4 = (tid & 1) * 4;
  const int arow = bm + lrow;
  const bool arow_ok = (arow < M);
  const int wk = tid >> 5, wn = (tid & 31) * 4;

  for (int k0 = 0; k0 < 128; k0 += 8) {
    float4 av = arow_ok ? *(const float4*)(A + (size_t)arow * 128 + k0 + lk4)
                        : make_float4(0.f, 0.f, 0.f, 0.f);
    As[lk4 + 0][lrow] = av.x;
    As[lk4 + 1][lrow] = av.y;
    As[lk4 + 2][lrow] = av.z;
    As[lk4 + 3][lrow] = av.w;
    *(float4*)(&Bs[wk][wn]) = *(const float4*)(W + (size_t)(k0 + wk) * 128 + wn);
    __syncthreads();
#pragma unroll
    for (int k = 0; k < 8; ++k) {
      float a[8], b[8];
      *(float4*)(a)     = *(const float4*)(&As[k][tr * 8]);
      *(float4*)(a + 4) = *(const float4*)(&As[k][tr * 8 + 4]);
      *(float4*)(b)     = *(const float4*)(&Bs[k][tc * 8]);
      *(float4*)(b + 4) = *(const float4*)(&Bs[k][tc * 8 + 4]);
#pragma unroll
      for (int i = 0; i < 8; ++i)
#pragma unroll
        for (int j = 0; j < 8; ++j) acc[i][j] += a[i] * b[j];
    }
    __syncthreads();
  }

#pragma unroll
  for (int i = 0; i < 8; ++i) {
    int row = bm + tr * 8 + i;
    if (row < M) {
      *(float4*)(Hout + (size_t)row * 128 + tc * 8) =
          make_float4(acc[i][0], acc[i][1], acc[i][2], acc[i][3]);
      *(float4*)(Hout + (size_t)row * 128 + tc * 8 + 4) =
          make_float4(acc[i][4], acc[i][5], acc[i][6], acc[i][7]);
    }
  }

  if (als != nullptr) {
    int h = tc >> 2;
    float asv[8], adv[8];
#pragma unroll
    for (int j = 0; j < 8; ++j) asv[j] = as_vec[tc * 8 + j];
    if (ald != nullptr)
#pragma unroll
      for (int j = 0; j < 8; ++j) adv[j] = ad_vec[tc * 8 + j];
#pragma unroll
    for (int i = 0; i < 8; ++i) {
      int row = bm + tr * 8 + i;
      float s1 = 0.f, s2 = 0.f;
#pragma unroll
      for (int j = 0; j < 8; ++j) {
        s1 += acc[i][j] * asv[j];
        if (ald != nullptr) s2 += acc[i][j] * adv[j];
      }
      s1 += __shfl_xor(s1, 1); s1 += __shfl_xor(s1, 2);
      if (ald != nullptr) { s2 += __shfl_xor(s2, 1); s2 += __shfl_xor(s2, 2); }
      if ((tc & 3) == 0 && row < M) {
        als[row * 4 + h] = s1;
        if (ald != nullptr) ald[row * 4 + h] = s2;
      }
    }
  }
}

// ----- ald[n,h] = sum_k x[n,k] * Vd[k,h]  (one wave per row) -----------------
__global__ __launch_bounds__(256) void gemv4(const float* __restrict__ x, int M,
                                             const float* __restrict__ Vd,
                                             float* __restrict__ out) {
  int lane = threadIdx.x & 63;
  int wid  = (blockIdx.x * blockDim.x + threadIdx.x) >> 6;
  int nw   = (gridDim.x * blockDim.x) >> 6;
  float4 v0 = *(const float4*)(Vd + 8 * lane);
  float4 v1 = *(const float4*)(Vd + 8 * lane + 4);
  for (int row = wid; row < M; row += nw) {
    float2 xv = *(const float2*)(x + (size_t)row * 128 + 2 * lane);
    float p0 = xv.x * v0.x + xv.y * v1.x;
    float p1 = xv.x * v0.y + xv.y * v1.y;
    float p2 = xv.x * v0.z + xv.y * v1.z;
    float p3 = xv.x * v0.w + xv.y * v1.w;
#pragma unroll
    for (int off = 32; off >= 1; off >>= 1) {
      p0 += __shfl_xor(p0, off);
      p1 += __shfl_xor(p1, off);
      p2 += __shfl_xor(p2, off);
      p3 += __shfl_xor(p3, off);
    }
    if (lane == 0) *(float4*)(out + 4 * (size_t)row) = make_float4(p0, p1, p2, p3);
  }
}

// ----- CSR build: histogram -> exclusive scan (single WG) -> scatter ---------
__global__ void hist_k(const int* __restrict__ ei, int E, int* __restrict__ cnt) {
  int i = blockIdx.x * blockDim.x + threadIdx.x;
  int stride = gridDim.x * blockDim.x;
  for (; i < E; i += stride) atomicAdd(cnt + ei[E + i], 1);
}

__global__ __launch_bounds__(1024) void scan_excl(const int* __restrict__ cnt, int n,
                                                  int* __restrict__ roff,
                                                  int* __restrict__ wp) {
  __shared__ int ps[1024];
  const int t = threadIdx.x;
  const int chunk = (n + 1023) >> 10;
  const int lo = t * chunk;
  const int hi = min(lo + chunk, n);
  int s = 0;
  for (int i = lo; i < hi; ++i) s += cnt[i];
  ps[t] = s;
  __syncthreads();
  for (int off = 1; off < 1024; off <<= 1) {
    int v = (t >= off) ? ps[t - off] : 0;
    __syncthreads();
    ps[t] += v;
    __syncthreads();
  }
  int run = ps[t] - s;  // exclusive base of this chunk
  for (int i = lo; i < hi; ++i) {
    roff[i] = run;
    wp[i]   = run;
    run += cnt[i];
  }
  if (t == 1023) roff[n] = ps[1023];
}

__global__ void scatter_k(const int* __restrict__ ei, int E,
                          int* __restrict__ wp, int* __restrict__ ssrc) {
  int i = blockIdx.x * blockDim.x + threadIdx.x;
  int stride = gridDim.x * blockDim.x;
  for (; i < E; i += stride) {
    int d = ei[E + i];
    int pos = atomicAdd(wp + d, 1);
    ssrc[pos] = ei[i];
  }
}

// ----- per-destination GAT aggregation (one wave per dest) -------------------
// lane l owns cols 2l,2l+1 (head h = l>>4). Returns alpha-weighted sum / den.
static __device__ __forceinline__ float2 gat_contrib(
    int d, int lane, int h,
    const int* __restrict__ roff, const int* __restrict__ ssrc,
    const float* __restrict__ als, const float* __restrict__ ald,
    const float* __restrict__ Hs) {
  int base = roff[d], end = roff[d + 1];
  if (base == end) return make_float2(0.f, 0.f);
  float4 ad4 = *(const float4*)(ald + 4 * (size_t)d);
  float aldh = (h == 0) ? ad4.x : (h == 1) ? ad4.y : (h == 2) ? ad4.z : ad4.w;

  // pass 1: per-head max over incoming edges (lane-parallel, then reduce)
  float mx0 = -1e30f, mx1 = -1e30f, mx2 = -1e30f, mx3 = -1e30f;
  for (int c = base + lane; c < end; c += 64) {
    int s = ssrc[c];
    float4 a = *(const float4*)(als + 4 * (size_t)s);
    float e0 = a.x + ad4.x; e0 = e0 > 0.f ? e0 : 0.2f * e0;
    float e1 = a.y + ad4.y; e1 = e1 > 0.f ? e1 : 0.2f * e1;
    float e2 = a.z + ad4.z; e2 = e2 > 0.f ? e2 : 0.2f * e2;
    float e3 = a.w + ad4.w; e3 = e3 > 0.f ? e3 : 0.2f * e3;
    mx0 = fmaxf(mx0, e0); mx1 = fmaxf(mx1, e1);
    mx2 = fmaxf(mx2, e2); mx3 = fmaxf(mx3, e3);
  }
#pragma unroll
  for (int off = 1; off < 64; off <<= 1) {
    mx0 = fmaxf(mx0, __shfl_xor(mx0, off));
    mx1 = fmaxf(mx1, __shfl_xor(mx1, off));
    mx2 = fmaxf(mx2, __shfl_xor(mx2, off));
    mx3 = fmaxf(mx3, __shfl_xor(mx3, off));
  }
  float m_own = (h == 0) ? mx0 : (h == 1) ? mx1 : (h == 2) ? mx2 : mx3;

  // pass 2: exp + den + weighted row gather (serial over edges, parallel cols)
  float acc0 = 0.f, acc1 = 0.f, den = 0.f;
  for (int c0 = base; c0 < end; c0 += 64) {
    int idx  = c0 + lane;
    int my_s = (idx < end) ? ssrc[idx] : 0;
    int cn   = min(64, end - c0);
    for (int j = 0; j < cn; ++j) {
      int s = __shfl(my_s, j);
      float v = als[4 * (size_t)s + h] + aldh;
      v = v > 0.f ? v : 0.2f * v;
      float ex = __expf(v - m_own);
      den += ex;
      float2 hv = *(const float2*)(Hs + (size_t)s * 128 + 2 * lane);
      acc0 += ex * hv.x;
      acc1 += ex * hv.y;
    }
  }
  float inv = 1.f / (den + 1e-16f);
  return make_float2(acc0 * inv, acc1 * inv);
}

// cell dests: sum of cc + ioc contributions + both biases, one write of Y
__global__ __launch_bounds__(256) void dest_agg_cell(
    const int* __restrict__ roff1, const int* __restrict__ ssrc1,
    const float* __restrict__ als1, const float* __restrict__ ald1,
    const float* __restrict__ H1, const float* __restrict__ b1,
    const int* __restrict__ roff2, const int* __restrict__ ssrc2,
    const float* __restrict__ als2, const float* __restrict__ ald2,
    const float* __restrict__ H2, const float* __restrict__ b2,
    float* __restrict__ Y, int M) {
  int lane = threadIdx.x & 63;
  int wid  = (blockIdx.x * blockDim.x + threadIdx.x) >> 6;
  int nw   = (gridDim.x * blockDim.x) >> 6;
  int h    = lane >> 4;
  float2 bb1 = *(const float2*)(b1 + 2 * lane);
  float2 bb2 = *(const float2*)(b2 + 2 * lane);
  for (int d = wid; d < M; d += nw) {
    float2 c1 = gat_contrib(d, lane, h, roff1, ssrc1, als1, ald1, H1);
    float2 c2 = gat_contrib(d, lane, h, roff2, ssrc2, als2, ald2, H2);
    *(float2*)(Y + (size_t)d * 128 + 2 * lane) =
        make_float2(c1.x + c2.x + bb1.x + bb2.x, c1.y + c2.y + bb1.y + bb2.y);
  }
}

__global__ __launch_bounds__(256) void dest_agg_io(
    const int* __restrict__ roff, const int* __restrict__ ssrc,
    const float* __restrict__ als, const float* __restrict__ ald,
    const float* __restrict__ H, const float* __restrict__ b,
    float* __restrict__ Y, int M) {
  int lane = threadIdx.x & 63;
  int wid  = (blockIdx.x * blockDim.x + threadIdx.x) >> 6;
  int nw   = (gridDim.x * blockDim.x) >> 6;
  int h    = lane >> 4;
  float2 bb = *(const float2*)(b + 2 * lane);
  for (int d = wid; d < M; d += nw) {
    float2 c = gat_contrib(d, lane, h, roff, ssrc, als, ald, H);
    *(float2*)(Y + (size_t)d * 128 + 2 * lane) = make_float2(c.x + bb.x, c.y + bb.y);
  }
}

// ----- fused transform: out = Y + relu(LN(Y@Wt + bt)*g + be) -----------------
__global__ __launch_bounds__(256) void transform_k(
    const float* __restrict__ Y, int M, const float* __restrict__ Wt,
    const float* __restrict__ bt, const float* __restrict__ g,
    const float* __restrict__ be, float* __restrict__ out) {
  __shared__ float As[8][128];
  __shared__ float Bs[8][128];
  const int bm  = blockIdx.x * 128;
  const int tid = threadIdx.x;
  const int tr = tid >> 4, tc = tid & 15;
  float acc[8][8];
#pragma unroll
  for (int i = 0; i < 8; ++i)
#pragma unroll
    for (int j = 0; j < 8; ++j) acc[i][j] = 0.f;

  const int lrow = tid >> 1, lk4 = (tid & 1) * 4;
  const int arow = bm + lrow;
  const bool arow_ok = (arow < M);
  const int wk = tid >> 5, wn = (tid & 31) * 4;

  for (int k0 = 0; k0 < 128; k0 += 8) {
    float4 av = arow_ok ? *(const float4*)(Y + (size_t)arow * 128 + k0 + lk4)
                        : make_float4(0.f, 0.f, 0.f, 0.f);
    As[lk4 + 0][lrow] = av.x;
    As[lk4 + 1][lrow] = av.y;
    As[lk4 + 2][lrow] = av.z;
    As[lk4 + 3][lrow] = av.w;
    *(float4*)(&Bs[wk][wn]) = *(const float4*)(Wt + (size_t)(k0 + wk) * 128 + wn);
    __syncthreads();
#pragma unroll
    for (int k = 0; k < 8; ++k) {
      float a[8], b[8];
      *(float4*)(a)     = *(const float4*)(&As[k][tr * 8]);
      *(float4*)(a + 4) = *(const float4*)(&As[k][tr * 8 + 4]);
      *(float4*)(b)     = *(const float4*)(&Bs[k][tc * 8]);
      *(float4*)(b + 4) = *(const float4*)(&Bs[k][tc * 8 + 4]);
#pragma unroll
      for (int i = 0; i < 8; ++i)
#pragma unroll
        for (int j = 0; j < 8; ++j) acc[i][j] += a[i] * b[j];
    }
    __syncthreads();
  }

  float btv[8], gv[8], bev[8];
#pragma unroll
  for (int j = 0; j < 8; ++j) {
    btv[j] = bt[tc * 8 + j];
    gv[j]  = g[tc * 8 + j];
    bev[j] = be[tc * 8 + j];
  }
#pragma unroll
  for (int i = 0; i < 8; ++i) {
    int row = bm + tr * 8 + i;
    float hv[8];
    float s = 0.f, ss = 0.f;
#pragma unroll
    for (int j = 0; j < 8; ++j) {
      hv[j] = acc[i][j] + btv[j];
      s += hv[j];
      ss += hv[j] * hv[j];
    }
#pragma unroll
    for (int off = 1; off <= 8; off <<= 1) {
      s  += __shfl_xor(s, off);
      ss += __shfl_xor(ss, off);
    }
    float mu  = s * (1.f / 128.f);
    float var = ss * (1.f / 128.f) - mu * mu;
    float rs  = rsqrtf(var + 1e-5f);
    if (row < M) {
      float4 y0 = *(const float4*)(Y + (size_t)row * 128 + tc * 8);
      float4 y1 = *(const float4*)(Y + (size_t)row * 128 + tc * 8 + 4);
      float yv[8] = {y0.x, y0.y, y0.z, y0.w, y1.x, y1.y, y1.z, y1.w};
      float ov[8];
#pragma unroll
      for (int j = 0; j < 8; ++j) {
        float hn = (hv[j] - mu) * rs * gv[j] + bev[j];
        ov[j] = yv[j] + (hn > 0.f ? hn : 0.f);
      }
      *(float4*)(out + (size_t)row * 128 + tc * 8) =
          make_float4(ov[0], ov[1], ov[2], ov[3]);
      *(float4*)(out + (size_t)row * 128 + tc * 8 + 4) =
          make_float4(ov[4], ov[5], ov[6], ov[7]);
    }
  }
}

// ---------------------------------------------------------------------------
extern "C" void kernel_launch(void* const* d_in, const int* in_sizes, int n_in,
                              void* d_out, int out_size, void* d_ws, size_t ws_size,
                              hipStream_t stream) {
  const float* x_cell = (const float*)d_in[0];
  const float* x_io   = (const float*)d_in[1];
  const int*   ei_cc  = (const int*)d_in[2];
  const int*   ei_cio = (const int*)d_in[3];
  const int*   ei_ioc = (const int*)d_in[4];
  const float* W_cc   = (const float*)d_in[5];
  const float* as_cc  = (const float*)d_in[6];
  const float* ad_cc  = (const float*)d_in[7];
  const float* b_cc   = (const float*)d_in[8];
  const float* W_cio  = (const float*)d_in[9];
  const float* as_cio = (const float*)d_in[10];
  const float* ad_cio = (const float*)d_in[11];
  const float* b_cio  = (const float*)d_in[12];
  const float* W_ioc  = (const float*)d_in[13];
  const float* as_ioc = (const float*)d_in[14];
  const float* ad_ioc = (const float*)d_in[15];
  const float* b_ioc  = (const float*)d_in[16];
  const float* Wt_cell = (const float*)d_in[17];
  const float* bt_cell = (const float*)d_in[18];
  const float* g_cell  = (const float*)d_in[19];
  const float* be_cell = (const float*)d_in[20];
  const float* Wt_io   = (const float*)d_in[21];
  const float* bt_io   = (const float*)d_in[22];
  const float* g_io    = (const float*)d_in[23];
  const float* be_io   = (const float*)d_in[24];

  float* out_cell = (float*)d_out;
  float* out_io   = (float*)d_out + (size_t)NC * 128;

  // ----- workspace layout -----
  float* w = (float*)d_ws;
  size_t o = 0;
  float* Hcc     = w + o; o += (size_t)NC * 128;
  float* Hcio    = w + o; o += (size_t)NC * 128;
  float* Hioc    = w + o; o += (size_t)NIO * 128;
  float* Ycell   = w + o; o += (size_t)NC * 128;
  float* Yio     = w + o; o += (size_t)NIO * 128;
  float* als_cc  = w + o; o += (size_t)NC * 4;
  float* ald_cc  = w + o; o += (size_t)NC * 4;
  float* als_cio = w + o; o += (size_t)NC * 4;
  float* ald_ioc = w + o; o += (size_t)NC * 4;
  float* als_ioc = w + o; o += (size_t)NIO * 4;
  float* ald_cio = w + o; o += (size_t)NIO * 4;
  float* Vd_ioc  = w + o; o += 512;
  float* Vd_cio  = w + o; o += 512;
  // int region
  int* ib = (int*)(w + o);
  size_t io_ = 0;
  int* cnt_cc   = ib + io_; io_ += NC;        // ---- contiguous zero region ----
  int* cnt_ioc  = ib + io_; io_ += NC;
  int* cnt_cio  = ib + io_; io_ += NIO;       // ---- end zero region ----
  int* roff_cc  = ib + io_; io_ += NC + 1;
  int* wp_cc    = ib + io_; io_ += NC;
  int* roff_ioc = ib + io_; io_ += NC + 1;
  int* wp_ioc   = ib + io_; io_ += NC;
  int* roff_cio = ib + io_; io_ += NIO + 1;
  int* wp_cio   = ib + io_; io_ += NIO;
  int* ssrc_cc  = ib + io_; io_ += ECC;
  int* ssrc_ioc = ib + io_; io_ += EIOC;
  int* ssrc_cio = ib + io_; io_ += ECIO;

  // 1. init counters + tiny precompute
  hipMemsetAsync(cnt_cc, 0, (size_t)(2 * NC + NIO) * sizeof(int), stream);
  vd_compute<<<4, 256, 0, stream>>>(W_ioc, ad_ioc, W_cio, ad_cio, Vd_ioc, Vd_cio);

  // 2. CSR build (3 relations)
  hist_k<<<2344, 256, 0, stream>>>(ei_cc, ECC, cnt_cc);
  hist_k<<<196, 256, 0, stream>>>(ei_ioc, EIOC, cnt_ioc);
  hist_k<<<196, 256, 0, stream>>>(ei_cio, ECIO, cnt_cio);
  scan_excl<<<1, 1024, 0, stream>>>(cnt_cc, NC, roff_cc, wp_cc);
  scan_excl<<<1, 1024, 0, stream>>>(cnt_ioc, NC, roff_ioc, wp_ioc);
  scan_excl<<<1, 1024, 0, stream>>>(cnt_cio, NIO, roff_cio, wp_cio);
  scatter_k<<<2344, 256, 0, stream>>>(ei_cc, ECC, wp_cc, ssrc_cc);
  scatter_k<<<196, 256, 0, stream>>>(ei_ioc, EIOC, wp_ioc, ssrc_ioc);
  scatter_k<<<196, 256, 0, stream>>>(ei_cio, ECIO, wp_cio, ssrc_cio);

  // 3. projections + fused logits
  gemm_h<<<(NC + 127) / 128, 256, 0, stream>>>(x_cell, NC, W_cc, Hcc,
                                               as_cc, als_cc, ad_cc, ald_cc);
  gemm_h<<<(NC + 127) / 128, 256, 0, stream>>>(x_cell, NC, W_cio, Hcio,
                                               as_cio, als_cio, nullptr, nullptr);
  gemm_h<<<(NIO + 127) / 128, 256, 0, stream>>>(x_io, NIO, W_ioc, Hioc,
                                                as_ioc, als_ioc, nullptr, nullptr);
  gemv4<<<2048, 256, 0, stream>>>(x_cell, NC, Vd_ioc, ald_ioc);
  gemv4<<<128, 256, 0, stream>>>(x_io, NIO, Vd_cio, ald_cio);

  // 4. per-dest aggregation (no float atomics, one write per dest row)
  dest_agg_cell<<<(NC + 3) / 4, 256, 0, stream>>>(
      roff_cc, ssrc_cc, als_cc, ald_cc, Hcc, b_cc,
      roff_ioc, ssrc_ioc, als_ioc, ald_ioc, Hioc, b_ioc, Ycell, NC);
  dest_agg_io<<<(NIO + 3) / 4, 256, 0, stream>>>(
      roff_cio, ssrc_cio, als_cio, ald_cio, Hcio, b_cio, Yio, NIO);

  // 5. transform (GEMM + LN + relu + residual) straight into d_out
  transform_k<<<(NC + 127) / 128, 256, 0, stream>>>(Ycell, NC, Wt_cell,
                                                    bt_cell, g_cell, be_cell,
                                                    out_cell);
  transform_k<<<(NIO + 127) / 128, 256, 0, stream>>>(Yio, NIO, Wt_io,
                                                     bt_io, g_io, be_io,
                                                     out_io);
}

// Round 3
// 618.915 us; speedup vs baseline: 2.9116x; 1.6925x over previous
//
#include <hip/hip_runtime.h>

// ---------------------------------------------------------------------------
// HeteroGNN (GAT x3 + transform x2) on MI355X — Round 3.
// R2 post-mortem: single-WG scan_excl = 2x229us (44% of 1047us), occupancy
// 0.15%. Fix: 3-phase device-wide scan over the CONCATENATED padded count
// array (relation bases are compile-time constants: 600000/50000/50000).
// Everything else unchanged from R2 (known-good).
// ---------------------------------------------------------------------------

#define NC   100000
#define NIO  2000
#define ECC  600000
#define ECIO 50000
#define EIOC 50000

// padded scan regions (multiples of 2048 so each scan block is single-relation)
#define PAD_CC   100352            // 49 * 2048  (cc counts)
#define PAD_IO   2048              // cio counts
#define NTOT_PAD (2 * PAD_CC + PAD_IO)   // 202752
#define SCAN_NBLK (NTOT_PAD / 2048)      // 99

// ----- Vd[k,h] = sum_c W[k, h*32+c]*ad[h*32+c]  (two matrices in one launch) -
__global__ void vd_compute(const float* __restrict__ W1, const float* __restrict__ ad1,
                           const float* __restrict__ W2, const float* __restrict__ ad2,
                           float* __restrict__ V1, float* __restrict__ V2) {
  int t = blockIdx.x * blockDim.x + threadIdx.x;
  if (t >= 1024) return;
  const float* W  = (t < 512) ? W1 : W2;
  const float* ad = (t < 512) ? ad1 : ad2;
  float*       V  = (t < 512) ? V1 : V2;
  int i = t & 511;
  int k = i >> 2, h = i & 3;
  float s = 0.f;
#pragma unroll
  for (int c = 0; c < 32; ++c) s += W[k * 128 + h * 32 + c] * ad[h * 32 + c];
  V[k * 4 + h] = s;
}

// ----- register-blocked fp32 GEMM: H[M,128] = A[M,128] @ W[128,128] ----------
__global__ __launch_bounds__(256) void gemm_h(
    const float* __restrict__ A, int M, const float* __restrict__ W,
    float* __restrict__ Hout,
    const float* __restrict__ as_vec, float* __restrict__ als,
    const float* __restrict__ ad_vec, float* __restrict__ ald) {
  __shared__ float As[8][128];
  __shared__ float Bs[8][128];
  const int bm  = blockIdx.x * 128;
  const int tid = threadIdx.x;
  const int tr = tid >> 4, tc = tid & 15;
  float acc[8][8];
#pragma unroll
  for (int i = 0; i < 8; ++i)
#pragma unroll
    for (int j = 0; j < 8; ++j) acc[i][j] = 0.f;

  const int lrow = tid >> 1, lk4 = (tid & 1) * 4;
  const int arow = bm + lrow;
  const bool arow_ok = (arow < M);
  const int wk = tid >> 5, wn = (tid & 31) * 4;

  for (int k0 = 0; k0 < 128; k0 += 8) {
    float4 av = arow_ok ? *(const float4*)(A + (size_t)arow * 128 + k0 + lk4)
                        : make_float4(0.f, 0.f, 0.f, 0.f);
    As[lk4 + 0][lrow] = av.x;
    As[lk4 + 1][lrow] = av.y;
    As[lk4 + 2][lrow] = av.z;
    As[lk4 + 3][lrow] = av.w;
    *(float4*)(&Bs[wk][wn]) = *(const float4*)(W + (size_t)(k0 + wk) * 128 + wn);
    __syncthreads();
#pragma unroll
    for (int k = 0; k < 8; ++k) {
      float a[8], b[8];
      *(float4*)(a)     = *(const float4*)(&As[k][tr * 8]);
      *(float4*)(a + 4) = *(const float4*)(&As[k][tr * 8 + 4]);
      *(float4*)(b)     = *(const float4*)(&Bs[k][tc * 8]);
      *(float4*)(b + 4) = *(const float4*)(&Bs[k][tc * 8 + 4]);
#pragma unroll
      for (int i = 0; i < 8; ++i)
#pragma unroll
        for (int j = 0; j < 8; ++j) acc[i][j] += a[i] * b[j];
    }
    __syncthreads();
  }

#pragma unroll
  for (int i = 0; i < 8; ++i) {
    int row = bm + tr * 8 + i;
    if (row < M) {
      *(float4*)(Hout + (size_t)row * 128 + tc * 8) =
          make_float4(acc[i][0], acc[i][1], acc[i][2], acc[i][3]);
      *(float4*)(Hout + (size_t)row * 128 + tc * 8 + 4) =
          make_float4(acc[i][4], acc[i][5], acc[i][6], acc[i][7]);
    }
  }

  if (als != nullptr) {
    int h = tc >> 2;
    float asv[8], adv[8];
#pragma unroll
    for (int j = 0; j < 8; ++j) asv[j] = as_vec[tc * 8 + j];
    if (ald != nullptr)
#pragma unroll
      for (int j = 0; j < 8; ++j) adv[j] = ad_vec[tc * 8 + j];
#pragma unroll
    for (int i = 0; i < 8; ++i) {
      int row = bm + tr * 8 + i;
      float s1 = 0.f, s2 = 0.f;
#pragma unroll
      for (int j = 0; j < 8; ++j) {
        s1 += acc[i][j] * asv[j];
        if (ald != nullptr) s2 += acc[i][j] * adv[j];
      }
      s1 += __shfl_xor(s1, 1); s1 += __shfl_xor(s1, 2);
      if (ald != nullptr) { s2 += __shfl_xor(s2, 1); s2 += __shfl_xor(s2, 2); }
      if ((tc & 3) == 0 && row < M) {
        als[row * 4 + h] = s1;
        if (ald != nullptr) ald[row * 4 + h] = s2;
      }
    }
  }
}

// ----- ald[n,h] = sum_k x[n,k] * Vd[k,h]  (one wave per row) -----------------
__global__ __launch_bounds__(256) void gemv4(const float* __restrict__ x, int M,
                                             const float* __restrict__ Vd,
                                             float* __restrict__ out) {
  int lane = threadIdx.x & 63;
  int wid  = (blockIdx.x * blockDim.x + threadIdx.x) >> 6;
  int nw   = (gridDim.x * blockDim.x) >> 6;
  float4 v0 = *(const float4*)(Vd + 8 * lane);
  float4 v1 = *(const float4*)(Vd + 8 * lane + 4);
  for (int row = wid; row < M; row += nw) {
    float2 xv = *(const float2*)(x + (size_t)row * 128 + 2 * lane);
    float p0 = xv.x * v0.x + xv.y * v1.x;
    float p1 = xv.x * v0.y + xv.y * v1.y;
    float p2 = xv.x * v0.z + xv.y * v1.z;
    float p3 = xv.x * v0.w + xv.y * v1.w;
#pragma unroll
    for (int off = 32; off >= 1; off >>= 1) {
      p0 += __shfl_xor(p0, off);
      p1 += __shfl_xor(p1, off);
      p2 += __shfl_xor(p2, off);
      p3 += __shfl_xor(p3, off);
    }
    if (lane == 0) *(float4*)(out + 4 * (size_t)row) = make_float4(p0, p1, p2, p3);
  }
}

// ----- CSR build: histogram -> 3-phase device-wide scan -> scatter -----------
__global__ void hist_k(const int* __restrict__ ei, int E, int* __restrict__ cnt) {
  int i = blockIdx.x * blockDim.x + threadIdx.x;
  int stride = gridDim.x * blockDim.x;
  for (; i < E; i += stride) atomicAdd(cnt + ei[E + i], 1);
}

// phase 1: per-block (2048 elems) sums
__global__ __launch_bounds__(1024) void scan_p1(const int* __restrict__ cnt,
                                                int* __restrict__ bsum) {
  int b = blockIdx.x, t = threadIdx.x;
  int2 c = *(const int2*)(cnt + (size_t)b * 2048 + 2 * t);
  int v = c.x + c.y;
#pragma unroll
  for (int off = 1; off < 64; off <<= 1) v += __shfl_xor(v, off);
  __shared__ int ws_[16];
  if ((t & 63) == 0) ws_[t >> 6] = v;
  __syncthreads();
  if (t < 16) {
    int x = ws_[t];
#pragma unroll
    for (int off = 1; off < 16; off <<= 1) x += __shfl_xor(x, off);
    if (t == 0) bsum[b] = x;
  }
}

// phase 2: exclusive scan of the 99 block sums (one 128-thread block)
__global__ __launch_bounds__(128) void scan_p2(int* __restrict__ bsum) {
  __shared__ int s[128];
  int t = threadIdx.x;
  int v = (t < SCAN_NBLK) ? bsum[t] : 0;
  s[t] = v;
  __syncthreads();
  for (int off = 1; off < 128; off <<= 1) {
    int u = (t >= off) ? s[t - off] : 0;
    __syncthreads();
    s[t] += u;
    __syncthreads();
  }
  if (t < SCAN_NBLK) bsum[t] = s[t] - v;  // exclusive
}

// phase 3: in-block exclusive scan + global base; route to per-relation roff/wp
__global__ __launch_bounds__(1024) void scan_p3(
    const int* __restrict__ cnt, const int* __restrict__ bsum,
    int* __restrict__ roff_cc, int* __restrict__ wp_cc,
    int* __restrict__ roff_ioc, int* __restrict__ wp_ioc,
    int* __restrict__ roff_cio, int* __restrict__ wp_cio) {
  int b = blockIdx.x, t = threadIdx.x;
  int gbase = b * 2048;
  int2 c = *(const int2*)(cnt + (size_t)gbase + 2 * t);
  int s = c.x + c.y;
  int lane = t & 63, wv = t >> 6;
  int inc = s;
#pragma unroll
  for (int off = 1; off < 64; off <<= 1) {
    int u = __shfl_up(inc, off);
    if (lane >= off) inc += u;
  }
  __shared__ int wsum[16];
  if (lane == 63) wsum[wv] = inc;
  __syncthreads();
  if (t == 0) {
    int run = 0;
#pragma unroll
    for (int i = 0; i < 16; ++i) { int x = wsum[i]; wsum[i] = run; run += x; }
  }
  __syncthreads();
  int excl = inc - s + wsum[wv] + bsum[b];

  int *roff, *wp;
  int rstart, rn, bsub;
  if (b < PAD_CC / 2048) {
    roff = roff_cc;  wp = wp_cc;  rstart = 0;          rn = NC;  bsub = 0;
  } else if (b < 2 * (PAD_CC / 2048)) {
    roff = roff_ioc; wp = wp_ioc; rstart = PAD_CC;     rn = NC;  bsub = ECC;
  } else {
    roff = roff_cio; wp = wp_cio; rstart = 2 * PAD_CC; rn = NIO; bsub = ECC + EIOC;
  }
  int li0 = gbase + 2 * t - rstart;
  int e0 = excl - bsub, e1 = excl + c.x - bsub;
  if (li0 < rn)     { roff[li0]     = e0; wp[li0]     = e0; }
  if (li0 + 1 < rn) { roff[li0 + 1] = e1; wp[li0 + 1] = e1; }
  if (b == 0 && t == 0) {
    roff_cc[NC]  = ECC;
    roff_ioc[NC] = EIOC;
    roff_cio[NIO] = ECIO;
  }
}

__global__ void scatter_k(const int* __restrict__ ei, int E,
                          int* __restrict__ wp, int* __restrict__ ssrc) {
  int i = blockIdx.x * blockDim.x + threadIdx.x;
  int stride = gridDim.x * blockDim.x;
  for (; i < E; i += stride) {
    int d = ei[E + i];
    int pos = atomicAdd(wp + d, 1);
    ssrc[pos] = ei[i];
  }
}

// ----- per-destination GAT aggregation (one wave per dest) -------------------
static __device__ __forceinline__ float2 gat_contrib(
    int d, int lane, int h,
    const int* __restrict__ roff, const int* __restrict__ ssrc,
    const float* __restrict__ als, const float* __restrict__ ald,
    const float* __restrict__ Hs) {
  int base = roff[d], end = roff[d + 1];
  if (base == end) return make_float2(0.f, 0.f);
  float4 ad4 = *(const float4*)(ald + 4 * (size_t)d);
  float aldh = (h == 0) ? ad4.x : (h == 1) ? ad4.y : (h == 2) ? ad4.z : ad4.w;

  float mx0 = -1e30f, mx1 = -1e30f, mx2 = -1e30f, mx3 = -1e30f;
  for (int c = base + lane; c < end; c += 64) {
    int s = ssrc[c];
    float4 a = *(const float4*)(als + 4 * (size_t)s);
    float e0 = a.x + ad4.x; e0 = e0 > 0.f ? e0 : 0.2f * e0;
    float e1 = a.y + ad4.y; e1 = e1 > 0.f ? e1 : 0.2f * e1;
    float e2 = a.z + ad4.z; e2 = e2 > 0.f ? e2 : 0.2f * e2;
    float e3 = a.w + ad4.w; e3 = e3 > 0.f ? e3 : 0.2f * e3;
    mx0 = fmaxf(mx0, e0); mx1 = fmaxf(mx1, e1);
    mx2 = fmaxf(mx2, e2); mx3 = fmaxf(mx3, e3);
  }
#pragma unroll
  for (int off = 1; off < 64; off <<= 1) {
    mx0 = fmaxf(mx0, __shfl_xor(mx0, off));
    mx1 = fmaxf(mx1, __shfl_xor(mx1, off));
    mx2 = fmaxf(mx2, __shfl_xor(mx2, off));
    mx3 = fmaxf(mx3, __shfl_xor(mx3, off));
  }
  float m_own = (h == 0) ? mx0 : (h == 1) ? mx1 : (h == 2) ? mx2 : mx3;

  float acc0 = 0.f, acc1 = 0.f, den = 0.f;
  for (int c0 = base; c0 < end; c0 += 64) {
    int idx  = c0 + lane;
    int my_s = (idx < end) ? ssrc[idx] : 0;
    int cn   = min(64, end - c0);
    for (int j = 0; j < cn; ++j) {
      int s = __shfl(my_s, j);
      float v = als[4 * (size_t)s + h] + aldh;
      v = v > 0.f ? v : 0.2f * v;
      float ex = __expf(v - m_own);
      den += ex;
      float2 hv = *(const float2*)(Hs + (size_t)s * 128 + 2 * lane);
      acc0 += ex * hv.x;
      acc1 += ex * hv.y;
    }
  }
  float inv = 1.f / (den + 1e-16f);
  return make_float2(acc0 * inv, acc1 * inv);
}

__global__ __launch_bounds__(256) void dest_agg_cell(
    const int* __restrict__ roff1, const int* __restrict__ ssrc1,
    const float* __restrict__ als1, const float* __restrict__ ald1,
    const float* __restrict__ H1, const float* __restrict__ b1,
    const int* __restrict__ roff2, const int* __restrict__ ssrc2,
    const float* __restrict__ als2, const float* __restrict__ ald2,
    const float* __restrict__ H2, const float* __restrict__ b2,
    float* __restrict__ Y, int M) {
  int lane = threadIdx.x & 63;
  int wid  = (blockIdx.x * blockDim.x + threadIdx.x) >> 6;
  int nw   = (gridDim.x * blockDim.x) >> 6;
  int h    = lane >> 4;
  float2 bb1 = *(const float2*)(b1 + 2 * lane);
  float2 bb2 = *(const float2*)(b2 + 2 * lane);
  for (int d = wid; d < M; d += nw) {
    float2 c1 = gat_contrib(d, lane, h, roff1, ssrc1, als1, ald1, H1);
    float2 c2 = gat_contrib(d, lane, h, roff2, ssrc2, als2, ald2, H2);
    *(float2*)(Y + (size_t)d * 128 + 2 * lane) =
        make_float2(c1.x + c2.x + bb1.x + bb2.x, c1.y + c2.y + bb1.y + bb2.y);
  }
}

__global__ __launch_bounds__(256) void dest_agg_io(
    const int* __restrict__ roff, const int* __restrict__ ssrc,
    const float* __restrict__ als, const float* __restrict__ ald,
    const float* __restrict__ H, const float* __restrict__ b,
    float* __restrict__ Y, int M) {
  int lane = threadIdx.x & 63;
  int wid  = (blockIdx.x * blockDim.x + threadIdx.x) >> 6;
  int nw   = (gridDim.x * blockDim.x) >> 6;
  int h    = lane >> 4;
  float2 bb = *(const float2*)(b + 2 * lane);
  for (int d = wid; d < M; d += nw) {
    float2 c = gat_contrib(d, lane, h, roff, ssrc, als, ald, H);
    *(float2*)(Y + (size_t)d * 128 + 2 * lane) = make_float2(c.x + bb.x, c.y + bb.y);
  }
}

// ----- fused transform: out = Y + relu(LN(Y@Wt + bt)*g + be) -----------------
__global__ __launch_bounds__(256) void transform_k(
    const float* __restrict__ Y, int M, const float* __restrict__ Wt,
    const float* __restrict__ bt, const float* __restrict__ g,
    const float* __restrict__ be, float* __restrict__ out) {
  __shared__ float As[8][128];
  __shared__ float Bs[8][128];
  const int bm  = blockIdx.x * 128;
  const int tid = threadIdx.x;
  const int tr = tid >> 4, tc = tid & 15;
  float acc[8][8];
#pragma unroll
  for (int i = 0; i < 8; ++i)
#pragma unroll
    for (int j = 0; j < 8; ++j) acc[i][j] = 0.f;

  const int lrow = tid >> 1, lk4 = (tid & 1) * 4;
  const int arow = bm + lrow;
  const bool arow_ok = (arow < M);
  const int wk = tid >> 5, wn = (tid & 31) * 4;

  for (int k0 = 0; k0 < 128; k0 += 8) {
    float4 av = arow_ok ? *(const float4*)(Y + (size_t)arow * 128 + k0 + lk4)
                        : make_float4(0.f, 0.f, 0.f, 0.f);
    As[lk4 + 0][lrow] = av.x;
    As[lk4 + 1][lrow] = av.y;
    As[lk4 + 2][lrow] = av.z;
    As[lk4 + 3][lrow] = av.w;
    *(float4*)(&Bs[wk][wn]) = *(const float4*)(Wt + (size_t)(k0 + wk) * 128 + wn);
    __syncthreads();
#pragma unroll
    for (int k = 0; k < 8; ++k) {
      float a[8], b[8];
      *(float4*)(a)     = *(const float4*)(&As[k][tr * 8]);
      *(float4*)(a + 4) = *(const float4*)(&As[k][tr * 8 + 4]);
      *(float4*)(b)     = *(const float4*)(&Bs[k][tc * 8]);
      *(float4*)(b + 4) = *(const float4*)(&Bs[k][tc * 8 + 4]);
#pragma unroll
      for (int i = 0; i < 8; ++i)
#pragma unroll
        for (int j = 0; j < 8; ++j) acc[i][j] += a[i] * b[j];
    }
    __syncthreads();
  }

  float btv[8], gv[8], bev[8];
#pragma unroll
  for (int j = 0; j < 8; ++j) {
    btv[j] = bt[tc * 8 + j];
    gv[j]  = g[tc * 8 + j];
    bev[j] = be[tc * 8 + j];
  }
#pragma unroll
  for (int i = 0; i < 8; ++i) {
    int row = bm + tr * 8 + i;
    float hv[8];
    float s = 0.f, ss = 0.f;
#pragma unroll
    for (int j = 0; j < 8; ++j) {
      hv[j] = acc[i][j] + btv[j];
      s += hv[j];
      ss += hv[j] * hv[j];
    }
#pragma unroll
    for (int off = 1; off <= 8; off <<= 1) {
      s  += __shfl_xor(s, off);
      ss += __shfl_xor(ss, off);
    }
    float mu  = s * (1.f / 128.f);
    float var = ss * (1.f / 128.f) - mu * mu;
    float rs  = rsqrtf(var + 1e-5f);
    if (row < M) {
      float4 y0 = *(const float4*)(Y + (size_t)row * 128 + tc * 8);
      float4 y1 = *(const float4*)(Y + (size_t)row * 128 + tc * 8 + 4);
      float yv[8] = {y0.x, y0.y, y0.z, y0.w, y1.x, y1.y, y1.z, y1.w};
      float ov[8];
#pragma unroll
      for (int j = 0; j < 8; ++j) {
        float hn = (hv[j] - mu) * rs * gv[j] + bev[j];
        ov[j] = yv[j] + (hn > 0.f ? hn : 0.f);
      }
      *(float4*)(out + (size_t)row * 128 + tc * 8) =
          make_float4(ov[0], ov[1], ov[2], ov[3]);
      *(float4*)(out + (size_t)row * 128 + tc * 8 + 4) =
          make_float4(ov[4], ov[5], ov[6], ov[7]);
    }
  }
}

// ---------------------------------------------------------------------------
extern "C" void kernel_launch(void* const* d_in, const int* in_sizes, int n_in,
                              void* d_out, int out_size, void* d_ws, size_t ws_size,
                              hipStream_t stream) {
  const float* x_cell = (const float*)d_in[0];
  const float* x_io   = (const float*)d_in[1];
  const int*   ei_cc  = (const int*)d_in[2];
  const int*   ei_cio = (const int*)d_in[3];
  const int*   ei_ioc = (const int*)d_in[4];
  const float* W_cc   = (const float*)d_in[5];
  const float* as_cc  = (const float*)d_in[6];
  const float* ad_cc  = (const float*)d_in[7];
  const float* b_cc   = (const float*)d_in[8];
  const float* W_cio  = (const float*)d_in[9];
  const float* as_cio = (const float*)d_in[10];
  const float* ad_cio = (const float*)d_in[11];
  const float* b_cio  = (const float*)d_in[12];
  const float* W_ioc  = (const float*)d_in[13];
  const float* as_ioc = (const float*)d_in[14];
  const float* ad_ioc = (const float*)d_in[15];
  const float* b_ioc  = (const float*)d_in[16];
  const float* Wt_cell = (const float*)d_in[17];
  const float* bt_cell = (const float*)d_in[18];
  const float* g_cell  = (const float*)d_in[19];
  const float* be_cell = (const float*)d_in[20];
  const float* Wt_io   = (const float*)d_in[21];
  const float* bt_io   = (const float*)d_in[22];
  const float* g_io    = (const float*)d_in[23];
  const float* be_io   = (const float*)d_in[24];

  float* out_cell = (float*)d_out;
  float* out_io   = (float*)d_out + (size_t)NC * 128;

  // ----- workspace layout -----
  float* w = (float*)d_ws;
  size_t o = 0;
  float* Hcc     = w + o; o += (size_t)NC * 128;
  float* Hcio    = w + o; o += (size_t)NC * 128;
  float* Hioc    = w + o; o += (size_t)NIO * 128;
  float* Ycell   = w + o; o += (size_t)NC * 128;
  float* Yio     = w + o; o += (size_t)NIO * 128;
  float* als_cc  = w + o; o += (size_t)NC * 4;
  float* ald_cc  = w + o; o += (size_t)NC * 4;
  float* als_cio = w + o; o += (size_t)NC * 4;
  float* ald_ioc = w + o; o += (size_t)NC * 4;
  float* als_ioc = w + o; o += (size_t)NIO * 4;
  float* ald_cio = w + o; o += (size_t)NIO * 4;
  float* Vd_ioc  = w + o; o += 512;
  float* Vd_cio  = w + o; o += 512;
  // int region (8B-aligned: all prior sizes are even)
  int* ib = (int*)(w + o);
  size_t io_ = 0;
  int* cnt_all  = ib + io_; io_ += NTOT_PAD;  // padded concat: cc | ioc | cio
  int* cnt_cc   = cnt_all;
  int* cnt_ioc  = cnt_all + PAD_CC;
  int* cnt_cio  = cnt_all + 2 * PAD_CC;
  int* bsum     = ib + io_; io_ += 128;
  int* roff_cc  = ib + io_; io_ += NC + 1;
  int* wp_cc    = ib + io_; io_ += NC;
  int* roff_ioc = ib + io_; io_ += NC + 1;
  int* wp_ioc   = ib + io_; io_ += NC;
  int* roff_cio = ib + io_; io_ += NIO + 1;
  int* wp_cio   = ib + io_; io_ += NIO;
  int* ssrc_cc  = ib + io_; io_ += ECC;
  int* ssrc_ioc = ib + io_; io_ += EIOC;
  int* ssrc_cio = ib + io_; io_ += ECIO;

  // 1. init counters (incl. padding) + tiny precompute
  hipMemsetAsync(cnt_all, 0, (size_t)NTOT_PAD * sizeof(int), stream);
  vd_compute<<<4, 256, 0, stream>>>(W_ioc, ad_ioc, W_cio, ad_cio, Vd_ioc, Vd_cio);

  // 2. CSR build (3 relations, one fused device-wide scan)
  hist_k<<<2344, 256, 0, stream>>>(ei_cc, ECC, cnt_cc);
  hist_k<<<196, 256, 0, stream>>>(ei_ioc, EIOC, cnt_ioc);
  hist_k<<<196, 256, 0, stream>>>(ei_cio, ECIO, cnt_cio);
  scan_p1<<<SCAN_NBLK, 1024, 0, stream>>>(cnt_all, bsum);
  scan_p2<<<1, 128, 0, stream>>>(bsum);
  scan_p3<<<SCAN_NBLK, 1024, 0, stream>>>(cnt_all, bsum,
                                          roff_cc, wp_cc,
                                          roff_ioc, wp_ioc,
                                          roff_cio, wp_cio);
  scatter_k<<<2344, 256, 0, stream>>>(ei_cc, ECC, wp_cc, ssrc_cc);
  scatter_k<<<196, 256, 0, stream>>>(ei_ioc, EIOC, wp_ioc, ssrc_ioc);
  scatter_k<<<196, 256, 0, stream>>>(ei_cio, ECIO, wp_cio, ssrc_cio);

  // 3. projections + fused logits
  gemm_h<<<(NC + 127) / 128, 256, 0, stream>>>(x_cell, NC, W_cc, Hcc,
                                               as_cc, als_cc, ad_cc, ald_cc);
  gemm_h<<<(NC + 127) / 128, 256, 0, stream>>>(x_cell, NC, W_cio, Hcio,
                                               as_cio, als_cio, nullptr, nullptr);
  gemm_h<<<(NIO + 127) / 128, 256, 0, stream>>>(x_io, NIO, W_ioc, Hioc,
                                                as_ioc, als_ioc, nullptr, nullptr);
  gemv4<<<2048, 256, 0, stream>>>(x_cell, NC, Vd_ioc, ald_ioc);
  gemv4<<<128, 256, 0, stream>>>(x_io, NIO, Vd_cio, ald_cio);

  // 4. per-dest aggregation (no float atomics, one write per dest row)
  dest_agg_cell<<<(NC + 3) / 4, 256, 0, stream>>>(
      roff_cc, ssrc_cc, als_cc, ald_cc, Hcc, b_cc,
      roff_ioc, ssrc_ioc, als_ioc, ald_ioc, Hioc, b_ioc, Ycell, NC);
  dest_agg_io<<<(NIO + 3) / 4, 256, 0, stream>>>(
      roff_cio, ssrc_cio, als_cio, ald_cio, Hcio, b_cio, Yio, NIO);

  // 5. transform (GEMM + LN + relu + residual) straight into d_out
  transform_k<<<(NC + 127) / 128, 256, 0, stream>>>(Ycell, NC, Wt_cell,
                                                    bt_cell, g_cell, be_cell,
                                                    out_cell);
  transform_k<<<(NIO + 127) / 128, 256, 0, stream>>>(Yio, NIO, Wt_io,
                                                     bt_io, g_io, be_io,
                                                     out_io);
}

// Round 8
// 472.084 us; speedup vs baseline: 3.8171x; 1.3110x over previous
//
#include <hip/hip_runtime.h>

// ---------------------------------------------------------------------------
// HeteroGNN (GAT x3 + transform x2) on MI355X — Round 8 (= R4, resubmitted
// after four GPU acquisition timeouts; source re-audited, unchanged).
// R3 post-mortem: dest_agg_cell 99us (VALU 60%); fp32 GEMMs ~VALU-bound;
// big fixed overhead from many launches. This round:
//  * dest_agg: drop segment-max (softmax shift-invariant; logits bounded ~6)
//  * all 5 GEMMs -> bf16-split (hi+lo) MFMA 16x16x32, 3-MFMA per fragment
//    (error ~1e-4), fused logit / LN+residual epilogues, swizzled LDS
//  * fuse hist x3, scatter x3, gemv x2; fold scan_p2 into p3; vd into prep_w
// ---------------------------------------------------------------------------

#define NC   100000
#define NIO  2000
#define ECC  600000
#define ECIO 50000
#define EIOC 50000

#define PAD_CC   100352                  // 49*2048
#define PAD_IO   2048
#define NTOT_PAD (2 * PAD_CC + PAD_IO)   // 202752
#define SCAN_NBLK (NTOT_PAD / 2048)      // 99

typedef unsigned short u16;
typedef short bf16x8 __attribute__((ext_vector_type(8)));
typedef float f32x4 __attribute__((ext_vector_type(4)));

static __device__ __forceinline__ u16 f2bf(float x) {  // RNE fp32->bf16 bits
  unsigned u = __float_as_uint(x);
  return (u16)((u + 0x7FFFu + ((u >> 16) & 1u)) >> 16);
}
static __device__ __forceinline__ float bf2f(u16 h) {
  return __uint_as_float(((unsigned)h) << 16);
}

// ----- prep: W -> transposed/split/swizzled bf16 images + Vd vectors ---------
// image per matrix: [kt(2)][n(128)][kg^= (n&7) chunks(8)][8] u16, hi then lo
__global__ __launch_bounds__(256) void prep_w(
    const float* __restrict__ W0, const float* __restrict__ W1,
    const float* __restrict__ W2, const float* __restrict__ W3,
    const float* __restrict__ W4, u16* __restrict__ wt,
    const float* __restrict__ ad_ioc, const float* __restrict__ ad_cio,
    float* __restrict__ Vd_ioc, float* __restrict__ Vd_cio) {
  int t = blockIdx.x * blockDim.x + threadIdx.x;     // 81920 threads
  int mat = t >> 14, e = t & 16383;
  int k = e >> 7, n = e & 127;
  const float* W = (mat == 0) ? W0 : (mat == 1) ? W1 : (mat == 2) ? W2
                 : (mat == 3) ? W3 : W4;
  float x = W[k * 128 + n];
  u16 h = f2bf(x);
  u16 l = f2bf(x - bf2f(h));
  int kt = k >> 6, kl = k & 63, kg = kl >> 3, j = kl & 7;
  int off = (kt * 128 + n) * 64 + ((kg ^ (n & 7)) * 8) + j;
  u16* base = wt + (size_t)mat * 32768;
  base[off] = h;
  base[16384 + off] = l;

  if (t < 1024) {  // Vd[k,h] = sum_c W[k, h*32+c]*ad[h*32+c]
    const float* Wv = (t < 512) ? W2 : W1;   // ioc then cio
    const float* ad = (t < 512) ? ad_ioc : ad_cio;
    float*       V  = (t < 512) ? Vd_ioc : Vd_cio;
    int i = t & 511, kk = i >> 2, hh = i & 3;
    float s = 0.f;
#pragma unroll
    for (int c = 0; c < 32; ++c) s += Wv[kk * 128 + hh * 32 + c] * ad[hh * 32 + c];
    V[kk * 4 + hh] = s;
  }
}

// ----- bf16-split MFMA GEMM: Out = A[M,128] @ W[128,128] ---------------------
// MODE 1: store H + per-head logits (als, optional ald)
// MODE 2: out = A + relu(LN(A@W + bt)*g + be)
template <int MODE>
__global__ __launch_bounds__(256) void mfma_gemm(
    const float* __restrict__ A, int M,
    const u16* __restrict__ WT,            // pre-split image (hi at 0, lo at +16384)
    float* __restrict__ Out,
    const float* __restrict__ as_vec, float* __restrict__ als,
    const float* __restrict__ ad_vec, float* __restrict__ ald,
    const float* __restrict__ bt, const float* __restrict__ gv_,
    const float* __restrict__ bev) {
  __shared__ u16 smem[32768];   // 64 KB: Ah | Al | Wh | Wl (16 KB each)
  u16* Ah = smem;
  u16* Al = smem + 8192;
  u16* Wh = smem + 16384;
  u16* Wl = smem + 24576;
  const int tid = threadIdx.x;
  const int bm = blockIdx.x * 128;
  const int lane = tid & 63;
  const int wv = tid >> 6;                 // 0..3
  const int qm = wv >> 1, qn = wv & 1;     // wave quadrant: 64 rows x 64 cols
  const int l15 = lane & 15, l4 = lane >> 4;

  f32x4 acc[4][4];
#pragma unroll
  for (int mi = 0; mi < 4; ++mi)
#pragma unroll
    for (int ni = 0; ni < 4; ++ni) acc[mi][ni] = {0.f, 0.f, 0.f, 0.f};

  for (int kt = 0; kt < 2; ++kt) {
    // stage A half-tile: fp32 -> hi/lo bf16, swizzled chunks
#pragma unroll
    for (int q = 0; q < 4; ++q) {
      int flat = q * 256 + tid;            // 1024 chunks of 8 floats
      int row = flat >> 3, kg = flat & 7;
      int grow = bm + row;
      float f[8];
      if (grow < M) {
        float4 v0 = *(const float4*)(A + (size_t)grow * 128 + kt * 64 + kg * 8);
        float4 v1 = *(const float4*)(A + (size_t)grow * 128 + kt * 64 + kg * 8 + 4);
        f[0] = v0.x; f[1] = v0.y; f[2] = v0.z; f[3] = v0.w;
        f[4] = v1.x; f[5] = v1.y; f[6] = v1.z; f[7] = v1.w;
      } else {
#pragma unroll
        for (int j = 0; j < 8; ++j) f[j] = 0.f;
      }
      union { bf16x8 v; u16 u[8]; } ph, pl;
#pragma unroll
      for (int j = 0; j < 8; ++j) {
        u16 h = f2bf(f[j]);
        ph.u[j] = h;
        pl.u[j] = f2bf(f[j] - bf2f(h));
      }
      int off = row * 64 + ((kg ^ (row & 7)) * 8);
      *(bf16x8*)(Ah + off) = ph.v;
      *(bf16x8*)(Al + off) = pl.v;
    }
    // stage W half-tile: straight copy (pre-swizzled global image)
    {
      const int4* sh = (const int4*)(WT + kt * 8192);
      const int4* sl = (const int4*)(WT + 16384 + kt * 8192);
#pragma unroll
      for (int q = 0; q < 4; ++q) {
        int idx = q * 256 + tid;
        ((int4*)Wh)[idx] = sh[idx];
        ((int4*)Wl)[idx] = sl[idx];
      }
    }
    __syncthreads();
#pragma unroll
    for (int kk = 0; kk < 2; ++kk) {
      bf16x8 ah[4], al[4], bh[4], bl[4];
#pragma unroll
      for (int mi = 0; mi < 4; ++mi) {
        int row = qm * 64 + mi * 16 + l15;
        int off = row * 64 + (((kk * 4 + l4) ^ (row & 7)) * 8);
        ah[mi] = *(const bf16x8*)(Ah + off);
        al[mi] = *(const bf16x8*)(Al + off);
      }
#pragma unroll
      for (int ni = 0; ni < 4; ++ni) {
        int n = qn * 64 + ni * 16 + l15;
        int off = n * 64 + (((kk * 4 + l4) ^ (n & 7)) * 8);
        bh[ni] = *(const bf16x8*)(Wh + off);
        bl[ni] = *(const bf16x8*)(Wl + off);
      }
#pragma unroll
      for (int mi = 0; mi < 4; ++mi)
#pragma unroll
        for (int ni = 0; ni < 4; ++ni) {
          acc[mi][ni] = __builtin_amdgcn_mfma_f32_16x16x32_bf16(
              ah[mi], bh[ni], acc[mi][ni], 0, 0, 0);
          acc[mi][ni] = __builtin_amdgcn_mfma_f32_16x16x32_bf16(
              ah[mi], bl[ni], acc[mi][ni], 0, 0, 0);
          acc[mi][ni] = __builtin_amdgcn_mfma_f32_16x16x32_bf16(
              al[mi], bh[ni], acc[mi][ni], 0, 0, 0);
        }
    }
    __syncthreads();
  }

  // D layout: col = lane&15, row = (lane>>4)*4 + reg   [guide-verified]
  if (MODE == 1) {
#pragma unroll
    for (int mi = 0; mi < 4; ++mi)
#pragma unroll
      for (int ni = 0; ni < 4; ++ni)
#pragma unroll
        for (int r = 0; r < 4; ++r) {
          int grow = bm + qm * 64 + mi * 16 + l4 * 4 + r;
          if (grow < M)
            Out[(size_t)grow * 128 + qn * 64 + ni * 16 + l15] = acc[mi][ni][r];
        }
    float asv[4], adv[4];
#pragma unroll
    for (int ni = 0; ni < 4; ++ni) {
      asv[ni] = as_vec[qn * 64 + ni * 16 + l15];
      adv[ni] = (ald != nullptr) ? ad_vec[qn * 64 + ni * 16 + l15] : 0.f;
    }
#pragma unroll
    for (int mi = 0; mi < 4; ++mi)
#pragma unroll
      for (int r = 0; r < 4; ++r) {
        float s0 = acc[mi][0][r] * asv[0] + acc[mi][1][r] * asv[1];
        float s1 = acc[mi][2][r] * asv[2] + acc[mi][3][r] * asv[3];
        float t0 = acc[mi][0][r] * adv[0] + acc[mi][1][r] * adv[1];
        float t1 = acc[mi][2][r] * adv[2] + acc[mi][3][r] * adv[3];
#pragma unroll
        for (int off = 1; off < 16; off <<= 1) {
          s0 += __shfl_xor(s0, off);
          s1 += __shfl_xor(s1, off);
          t0 += __shfl_xor(t0, off);
          t1 += __shfl_xor(t1, off);
        }
        if (l15 == 0) {
          int grow = bm + qm * 64 + mi * 16 + l4 * 4 + r;
          if (grow < M) {
            als[(size_t)grow * 4 + qn * 2]     = s0;
            als[(size_t)grow * 4 + qn * 2 + 1] = s1;
            if (ald != nullptr) {
              ald[(size_t)grow * 4 + qn * 2]     = t0;
              ald[(size_t)grow * 4 + qn * 2 + 1] = t1;
            }
          }
        }
      }
  } else {  // MODE 2: LN + relu + residual
    float btv[4], gvv[4], bevv[4];
#pragma unroll
    for (int ni = 0; ni < 4; ++ni) {
      int col = qn * 64 + ni * 16 + l15;
      btv[ni] = bt[col]; gvv[ni] = gv_[col]; bevv[ni] = bev[col];
    }
    float* part = (float*)(smem + 16384);  // reuse W area: [128 rows][2 qn][2]
#pragma unroll
    for (int mi = 0; mi < 4; ++mi)
#pragma unroll
      for (int r = 0; r < 4; ++r) {
        float hs = 0.f, hss = 0.f;
#pragma unroll
        for (int ni = 0; ni < 4; ++ni) {
          float hv = acc[mi][ni][r] + btv[ni];
          hs += hv; hss += hv * hv;
        }
#pragma unroll
        for (int off = 1; off < 16; off <<= 1) {
          hs += __shfl_xor(hs, off);
          hss += __shfl_xor(hss, off);
        }
        if (l15 == 0) {
          int rl = qm * 64 + mi * 16 + l4 * 4 + r;
          part[rl * 4 + qn * 2]     = hs;
          part[rl * 4 + qn * 2 + 1] = hss;
        }
      }
    __syncthreads();
#pragma unroll
    for (int mi = 0; mi < 4; ++mi)
#pragma unroll
      for (int r = 0; r < 4; ++r) {
        int rl = qm * 64 + mi * 16 + l4 * 4 + r;
        int grow = bm + rl;
        float s  = part[rl * 4] + part[rl * 4 + 2];
        float ss = part[rl * 4 + 1] + part[rl * 4 + 3];
        float mu = s * (1.f / 128.f);
        float var = ss * (1.f / 128.f) - mu * mu;
        float rs = rsqrtf(var + 1e-5f);
        if (grow < M) {
#pragma unroll
          for (int ni = 0; ni < 4; ++ni) {
            int col = qn * 64 + ni * 16 + l15;
            float y = A[(size_t)grow * 128 + col];
            float hv = acc[mi][ni][r] + btv[ni];
            float hn = (hv - mu) * rs * gvv[ni] + bevv[ni];
            Out[(size_t)grow * 128 + col] = y + (hn > 0.f ? hn : 0.f);
          }
        }
      }
  }
}

// ----- fused gemv: ald = x @ Vd for both node types --------------------------
__global__ __launch_bounds__(256) void gemv_all(
    const float* __restrict__ x_cell, const float* __restrict__ x_io,
    const float* __restrict__ Vd_ioc, const float* __restrict__ Vd_cio,
    float* __restrict__ ald_ioc, float* __restrict__ ald_cio) {
  int lane = threadIdx.x & 63;
  int wid  = (blockIdx.x * blockDim.x + threadIdx.x) >> 6;
  int nw   = (gridDim.x * blockDim.x) >> 6;
  for (int row = wid; row < NC + NIO; row += nw) {
    const float* xr; const float* Vd; float* o;
    if (row < NC) { xr = x_cell + (size_t)row * 128; Vd = Vd_ioc; o = ald_ioc + 4 * (size_t)row; }
    else { int r2 = row - NC; xr = x_io + (size_t)r2 * 128; Vd = Vd_cio; o = ald_cio + 4 * (size_t)r2; }
    float4 v0 = *(const float4*)(Vd + 8 * lane);
    float4 v1 = *(const float4*)(Vd + 8 * lane + 4);
    float2 xv = *(const float2*)(xr + 2 * lane);
    float p0 = xv.x * v0.x + xv.y * v1.x;
    float p1 = xv.x * v0.y + xv.y * v1.y;
    float p2 = xv.x * v0.z + xv.y * v1.z;
    float p3 = xv.x * v0.w + xv.y * v1.w;
#pragma unroll
    for (int off = 32; off >= 1; off >>= 1) {
      p0 += __shfl_xor(p0, off);
      p1 += __shfl_xor(p1, off);
      p2 += __shfl_xor(p2, off);
      p3 += __shfl_xor(p3, off);
    }
    if (lane == 0) *(float4*)o = make_float4(p0, p1, p2, p3);
  }
}

// ----- CSR build -------------------------------------------------------------
__global__ void hist_all(const int* __restrict__ ei_cc, const int* __restrict__ ei_ioc,
                         const int* __restrict__ ei_cio,
                         int* __restrict__ c_cc, int* __restrict__ c_ioc,
                         int* __restrict__ c_cio) {
  int i = blockIdx.x * blockDim.x + threadIdx.x;
  if (i < ECC) atomicAdd(c_cc + ei_cc[ECC + i], 1);
  else if (i < ECC + EIOC) { int j = i - ECC; atomicAdd(c_ioc + ei_ioc[EIOC + j], 1); }
  else if (i < ECC + EIOC + ECIO) { int j = i - ECC - EIOC; atomicAdd(c_cio + ei_cio[ECIO + j], 1); }
}

__global__ __launch_bounds__(1024) void scan_p1(const int* __restrict__ cnt,
                                                int* __restrict__ bsum) {
  int b = blockIdx.x, t = threadIdx.x;
  int2 c = *(const int2*)(cnt + (size_t)b * 2048 + 2 * t);
  int v = c.x + c.y;
#pragma unroll
  for (int off = 1; off < 64; off <<= 1) v += __shfl_xor(v, off);
  __shared__ int ws_[16];
  if ((t & 63) == 0) ws_[t >> 6] = v;
  __syncthreads();
  if (t < 16) {
    int x = ws_[t];
#pragma unroll
    for (int off = 1; off < 16; off <<= 1) x += __shfl_xor(x, off);
    if (t == 0) bsum[b] = x;
  }
}

// phase 3 with folded top-level scan of the 99 raw block sums
__global__ __launch_bounds__(1024) void scan_p3(
    const int* __restrict__ cnt, const int* __restrict__ bsum,
    int* __restrict__ roff_cc, int* __restrict__ wp_cc,
    int* __restrict__ roff_ioc, int* __restrict__ wp_ioc,
    int* __restrict__ roff_cio, int* __restrict__ wp_cio) {
  int b = blockIdx.x, t = threadIdx.x;
  __shared__ int topbase_s;
  if (t < 64) {
    int s = 0;
    if (t < b) s += bsum[t];
    if (t + 64 < b) s += bsum[t + 64];
#pragma unroll
    for (int off = 1; off < 64; off <<= 1) s += __shfl_xor(s, off);
    if (t == 0) topbase_s = s;
  }
  int gbase = b * 2048;
  int2 c = *(const int2*)(cnt + (size_t)gbase + 2 * t);
  int s = c.x + c.y;
  int lane = t & 63, wv = t >> 6;
  int inc = s;
#pragma unroll
  for (int off = 1; off < 64; off <<= 1) {
    int u = __shfl_up(inc, off);
    if (lane >= off) inc += u;
  }
  __shared__ int wsum[16];
  if (lane == 63) wsum[wv] = inc;
  __syncthreads();
  if (t == 0) {
    int run = 0;
#pragma unroll
    for (int i = 0; i < 16; ++i) { int x = wsum[i]; wsum[i] = run; run += x; }
  }
  __syncthreads();
  int excl = inc - s + wsum[wv] + topbase_s;

  int *roff, *wp;
  int rstart, rn, bsub;
  if (b < PAD_CC / 2048) {
    roff = roff_cc;  wp = wp_cc;  rstart = 0;          rn = NC;  bsub = 0;
  } else if (b < 2 * (PAD_CC / 2048)) {
    roff = roff_ioc; wp = wp_ioc; rstart = PAD_CC;     rn = NC;  bsub = ECC;
  } else {
    roff = roff_cio; wp = wp_cio; rstart = 2 * PAD_CC; rn = NIO; bsub = ECC + EIOC;
  }
  int li0 = gbase + 2 * t - rstart;
  int e0 = excl - bsub, e1 = excl + c.x - bsub;
  if (li0 < rn)     { roff[li0]     = e0; wp[li0]     = e0; }
  if (li0 + 1 < rn) { roff[li0 + 1] = e1; wp[li0 + 1] = e1; }
  if (b == 0 && t == 0) {
    roff_cc[NC]   = ECC;
    roff_ioc[NC]  = EIOC;
    roff_cio[NIO] = ECIO;
  }
}

__global__ void scatter_all(const int* __restrict__ ei_cc, const int* __restrict__ ei_ioc,
                            const int* __restrict__ ei_cio,
                            int* __restrict__ wp_cc, int* __restrict__ wp_ioc,
                            int* __restrict__ wp_cio,
                            int* __restrict__ s_cc, int* __restrict__ s_ioc,
                            int* __restrict__ s_cio) {
  int i = blockIdx.x * blockDim.x + threadIdx.x;
  if (i < ECC) {
    int d = ei_cc[ECC + i];
    s_cc[atomicAdd(wp_cc + d, 1)] = ei_cc[i];
  } else if (i < ECC + EIOC) {
    int j = i - ECC;
    int d = ei_ioc[EIOC + j];
    s_ioc[atomicAdd(wp_ioc + d, 1)] = ei_ioc[j];
  } else if (i < ECC + EIOC + ECIO) {
    int j = i - ECC - EIOC;
    int d = ei_cio[ECIO + j];
    s_cio[atomicAdd(wp_cio + d, 1)] = ei_cio[j];
  }
}

// ----- per-destination GAT aggregation, no max pass (shift-invariant) --------
static __device__ __forceinline__ float2 gat_contrib(
    int d, int lane, int h,
    const int* __restrict__ roff, const int* __restrict__ ssrc,
    const float* __restrict__ als, const float* __restrict__ ald,
    const float* __restrict__ Hs) {
  int base = roff[d], end = roff[d + 1];
  if (base == end) return make_float2(0.f, 0.f);
  float aldh = ald[4 * (size_t)d + h];
  float acc0 = 0.f, acc1 = 0.f, den = 0.f;
  for (int c0 = base; c0 < end; c0 += 64) {
    int idx  = c0 + lane;
    int my_s = (idx < end) ? ssrc[idx] : 0;
    int cn   = min(64, end - c0);
    for (int j = 0; j < cn; ++j) {
      int s = __shfl(my_s, j);
      float v = als[4 * (size_t)s + h] + aldh;
      v = v > 0.f ? v : 0.2f * v;
      float ex = __expf(v);
      den += ex;
      float2 hv = *(const float2*)(Hs + (size_t)s * 128 + 2 * lane);
      acc0 += ex * hv.x;
      acc1 += ex * hv.y;
    }
  }
  float inv = 1.f / (den + 1e-16f);
  return make_float2(acc0 * inv, acc1 * inv);
}

__global__ __launch_bounds__(256) void dest_agg_cell(
    const int* __restrict__ roff1, const int* __restrict__ ssrc1,
    const float* __restrict__ als1, const float* __restrict__ ald1,
    const float* __restrict__ H1, const float* __restrict__ b1,
    const int* __restrict__ roff2, const int* __restrict__ ssrc2,
    const float* __restrict__ als2, const float* __restrict__ ald2,
    const float* __restrict__ H2, const float* __restrict__ b2,
    float* __restrict__ Y, int M) {
  int lane = threadIdx.x & 63;
  int wid  = (blockIdx.x * blockDim.x + threadIdx.x) >> 6;
  int nw   = (gridDim.x * blockDim.x) >> 6;
  int h    = lane >> 4;
  float2 bb1 = *(const float2*)(b1 + 2 * lane);
  float2 bb2 = *(const float2*)(b2 + 2 * lane);
  for (int d = wid; d < M; d += nw) {
    float2 c1 = gat_contrib(d, lane, h, roff1, ssrc1, als1, ald1, H1);
    float2 c2 = gat_contrib(d, lane, h, roff2, ssrc2, als2, ald2, H2);
    *(float2*)(Y + (size_t)d * 128 + 2 * lane) =
        make_float2(c1.x + c2.x + bb1.x + bb2.x, c1.y + c2.y + bb1.y + bb2.y);
  }
}

__global__ __launch_bounds__(256) void dest_agg_io(
    const int* __restrict__ roff, const int* __restrict__ ssrc,
    const float* __restrict__ als, const float* __restrict__ ald,
    const float* __restrict__ H, const float* __restrict__ b,
    float* __restrict__ Y, int M) {
  int lane = threadIdx.x & 63;
  int wid  = (blockIdx.x * blockDim.x + threadIdx.x) >> 6;
  int nw   = (gridDim.x * blockDim.x) >> 6;
  int h    = lane >> 4;
  float2 bb = *(const float2*)(b + 2 * lane);
  for (int d = wid; d < M; d += nw) {
    float2 c = gat_contrib(d, lane, h, roff, ssrc, als, ald, H);
    *(float2*)(Y + (size_t)d * 128 + 2 * lane) = make_float2(c.x + bb.x, c.y + bb.y);
  }
}

// ---------------------------------------------------------------------------
extern "C" void kernel_launch(void* const* d_in, const int* in_sizes, int n_in,
                              void* d_out, int out_size, void* d_ws, size_t ws_size,
                              hipStream_t stream) {
  const float* x_cell = (const float*)d_in[0];
  const float* x_io   = (const float*)d_in[1];
  const int*   ei_cc  = (const int*)d_in[2];
  const int*   ei_cio = (const int*)d_in[3];
  const int*   ei_ioc = (const int*)d_in[4];
  const float* W_cc   = (const float*)d_in[5];
  const float* as_cc  = (const float*)d_in[6];
  const float* ad_cc  = (const float*)d_in[7];
  const float* b_cc   = (const float*)d_in[8];
  const float* W_cio  = (const float*)d_in[9];
  const float* as_cio = (const float*)d_in[10];
  const float* ad_cio = (const float*)d_in[11];
  const float* b_cio  = (const float*)d_in[12];
  const float* W_ioc  = (const float*)d_in[13];
  const float* as_ioc = (const float*)d_in[14];
  const float* ad_ioc = (const float*)d_in[15];
  const float* b_ioc  = (const float*)d_in[16];
  const float* Wt_cell = (const float*)d_in[17];
  const float* bt_cell = (const float*)d_in[18];
  const float* g_cell  = (const float*)d_in[19];
  const float* be_cell = (const float*)d_in[20];
  const float* Wt_io   = (const float*)d_in[21];
  const float* bt_io   = (const float*)d_in[22];
  const float* g_io    = (const float*)d_in[23];
  const float* be_io   = (const float*)d_in[24];

  float* out_cell = (float*)d_out;
  float* out_io   = (float*)d_out + (size_t)NC * 128;

  // ----- workspace layout -----
  float* w = (float*)d_ws;
  size_t o = 0;
  float* Hcc     = w + o; o += (size_t)NC * 128;
  float* Hcio    = w + o; o += (size_t)NC * 128;
  float* Hioc    = w + o; o += (size_t)NIO * 128;
  float* Ycell   = w + o; o += (size_t)NC * 128;
  float* Yio     = w + o; o += (size_t)NIO * 128;
  float* als_cc  = w + o; o += (size_t)NC * 4;
  float* ald_cc  = w + o; o += (size_t)NC * 4;
  float* als_cio = w + o; o += (size_t)NC * 4;
  float* ald_ioc = w + o; o += (size_t)NC * 4;
  float* als_ioc = w + o; o += (size_t)NIO * 4;
  float* ald_cio = w + o; o += (size_t)NIO * 4;
  float* Vd_ioc  = w + o; o += 512;
  float* Vd_cio  = w + o; o += 512;
  u16* wt_base   = (u16*)(w + o); o += 81920;   // 5 mats x 32768 u16 (hi|lo)
  int* ib = (int*)(w + o);
  size_t io_ = 0;
  int* cnt_all  = ib + io_; io_ += NTOT_PAD;
  int* cnt_cc   = cnt_all;
  int* cnt_ioc  = cnt_all + PAD_CC;
  int* cnt_cio  = cnt_all + 2 * PAD_CC;
  int* bsum     = ib + io_; io_ += 128;
  int* roff_cc  = ib + io_; io_ += NC + 1;
  int* wp_cc    = ib + io_; io_ += NC;
  int* roff_ioc = ib + io_; io_ += NC + 1;
  int* wp_ioc   = ib + io_; io_ += NC;
  int* roff_cio = ib + io_; io_ += NIO + 1;
  int* wp_cio   = ib + io_; io_ += NIO;
  int* ssrc_cc  = ib + io_; io_ += ECC;
  int* ssrc_ioc = ib + io_; io_ += EIOC;
  int* ssrc_cio = ib + io_; io_ += ECIO;

  u16* WT_cc  = wt_base;
  u16* WT_cio = wt_base + 32768;
  u16* WT_ioc = wt_base + 2 * 32768;
  u16* WT_tc  = wt_base + 3 * 32768;
  u16* WT_ti  = wt_base + 4 * 32768;

  // 1. init + prep (W split images + Vd)
  hipMemsetAsync(cnt_all, 0, (size_t)NTOT_PAD * sizeof(int), stream);
  prep_w<<<320, 256, 0, stream>>>(W_cc, W_cio, W_ioc, Wt_cell, Wt_io, wt_base,
                                  ad_ioc, ad_cio, Vd_ioc, Vd_cio);

  // 2. CSR build
  hist_all<<<(ECC + EIOC + ECIO + 255) / 256, 256, 0, stream>>>(
      ei_cc, ei_ioc, ei_cio, cnt_cc, cnt_ioc, cnt_cio);
  scan_p1<<<SCAN_NBLK, 1024, 0, stream>>>(cnt_all, bsum);
  scan_p3<<<SCAN_NBLK, 1024, 0, stream>>>(cnt_all, bsum, roff_cc, wp_cc,
                                          roff_ioc, wp_ioc, roff_cio, wp_cio);
  scatter_all<<<(ECC + EIOC + ECIO + 255) / 256, 256, 0, stream>>>(
      ei_cc, ei_ioc, ei_cio, wp_cc, wp_ioc, wp_cio, ssrc_cc, ssrc_ioc, ssrc_cio);

  // 3. projections (bf16-split MFMA) + fused logits, plus ald gemv
  mfma_gemm<1><<<(NC + 127) / 128, 256, 0, stream>>>(
      x_cell, NC, WT_cc, Hcc, as_cc, als_cc, ad_cc, ald_cc,
      nullptr, nullptr, nullptr);
  mfma_gemm<1><<<(NC + 127) / 128, 256, 0, stream>>>(
      x_cell, NC, WT_cio, Hcio, as_cio, als_cio, nullptr, nullptr,
      nullptr, nullptr, nullptr);
  mfma_gemm<1><<<(NIO + 127) / 128, 256, 0, stream>>>(
      x_io, NIO, WT_ioc, Hioc, as_ioc, als_ioc, nullptr, nullptr,
      nullptr, nullptr, nullptr);
  gemv_all<<<2048, 256, 0, stream>>>(x_cell, x_io, Vd_ioc, Vd_cio,
                                     ald_ioc, ald_cio);

  // 4. per-dest aggregation (single pass, no float atomics)
  dest_agg_cell<<<(NC + 3) / 4, 256, 0, stream>>>(
      roff_cc, ssrc_cc, als_cc, ald_cc, Hcc, b_cc,
      roff_ioc, ssrc_ioc, als_ioc, ald_ioc, Hioc, b_ioc, Ycell, NC);
  dest_agg_io<<<(NIO + 3) / 4, 256, 0, stream>>>(
      roff_cio, ssrc_cio, als_cio, ald_cio, Hcio, b_cio, Yio, NIO);

  // 5. transform (MFMA GEMM + LN + relu + residual) into d_out
  mfma_gemm<2><<<(NC + 127) / 128, 256, 0, stream>>>(
      Ycell, NC, WT_tc, out_cell, nullptr, nullptr, nullptr, nullptr,
      bt_cell, g_cell, be_cell);
  mfma_gemm<2><<<(NIO + 127) / 128, 256, 0, stream>>>(
      Yio, NIO, WT_ti, out_io, nullptr, nullptr, nullptr, nullptr,
      bt_io, g_io, be_io);
}